// Round 2
// baseline (11014.772 us; speedup 1.0000x reference)
//
#include <hip/hip_runtime.h>
#include <hip/hip_bf16.h>

// ---------------------------------------------------------------------------
// GAT encoder: 2x GATConv + BatchNorm/ReLU. N=50000, E=800000(+N self loops),
// Fin=256, H=4, C=64, L=64. All fp32.
// Workspace budget: 2 x 51.2MB big buffers + ~2.5MB small = ~105MB.
// Attention alpha is recomputed inside the aggregate kernels (no stored
// per-edge weights); layer-2 head-mean is fused into the atomic scatter.
// ---------------------------------------------------------------------------

#define HC 256   // H*C
#define NH 4     // heads
#define LRELU_SLOPE 0.2f
#define BN_EPS 1e-5f

// -------------------- edge-index dtype detection (int32 vs int64) ----------
__global__ void detect_k(const int* __restrict__ ei, long long E, int* __restrict__ flag) {
    __shared__ int any;
    if (threadIdx.x == 0) any = 0;
    __syncthreads();
    for (int i = threadIdx.x; i < 1024; i += blockDim.x) {
        long long idx = 2LL * i + 1;                 // hi-word position if int64
        if (idx < 2 * E && ei[idx] != 0) atomicOr(&any, 1);
    }
    __syncthreads();
    if (threadIdx.x == 0) flag[0] = (any == 0) ? 1 : 0;   // 1 => int64 layout
}

__device__ __forceinline__ void load_edge(const int* __restrict__ ei, int flag64,
                                          long long E, long long e, int& s, int& d) {
    if (e >= E) { s = d = (int)(e - E); return; }        // appended self-loops
    if (flag64) { s = ei[2 * e]; d = ei[2 * E + 2 * e]; }
    else        { s = ei[e];     d = ei[E + e]; }
}

__device__ __forceinline__ float edge_alpha(const float* __restrict__ esrc,
                                            const float* __restrict__ edst,
                                            const float* __restrict__ denom,
                                            int s, int d, int head) {
    float t = esrc[(long long)s * NH + head] + edst[(long long)d * NH + head];
    t = t >= 0.f ? t : LRELU_SLOPE * t;
    return __expf(t) / denom[(long long)d * NH + head];
}

// -------------------- tiled fp32 GEMM: C[M,Nn] = A[M,K] @ B[K,Nn] ----------
#define GTM 64
#define GTN 64
#define GTK 16
__global__ __launch_bounds__(256) void gemm_k(const float* __restrict__ A,
                                              const float* __restrict__ B,
                                              float* __restrict__ C,
                                              int M, int Nn, int K) {
    __shared__ float As[GTM][GTK + 1];
    __shared__ float Bs[GTK][GTN + 1];
    const int mt = blockIdx.y * GTM;
    const int nt = blockIdx.x * GTN;
    const int t  = threadIdx.x;
    const int tx = t & 15, ty = t >> 4;
    float acc[4][4] = {};
    for (int k0 = 0; k0 < K; k0 += GTK) {
        {   // A tile: 64x16, one float4 per thread
            int r = t >> 2, c = (t & 3) * 4;
            int gr = mt + r;
            float4 v = (gr < M) ? *(const float4*)&A[(long long)gr * K + k0 + c]
                                : make_float4(0.f, 0.f, 0.f, 0.f);
            As[r][c] = v.x; As[r][c + 1] = v.y; As[r][c + 2] = v.z; As[r][c + 3] = v.w;
        }
        {   // B tile: 16x64, one float4 per thread
            int r = t >> 4, c = (t & 15) * 4;
            float4 v = *(const float4*)&B[(long long)(k0 + r) * Nn + nt + c];
            Bs[r][c] = v.x; Bs[r][c + 1] = v.y; Bs[r][c + 2] = v.z; Bs[r][c + 3] = v.w;
        }
        __syncthreads();
#pragma unroll
        for (int kk = 0; kk < GTK; ++kk) {
            float a[4], b[4];
#pragma unroll
            for (int i = 0; i < 4; ++i) a[i] = As[ty * 4 + i][kk];
#pragma unroll
            for (int j = 0; j < 4; ++j) b[j] = Bs[kk][tx * 4 + j];
#pragma unroll
            for (int i = 0; i < 4; ++i)
#pragma unroll
                for (int j = 0; j < 4; ++j) acc[i][j] = fmaf(a[i], b[j], acc[i][j]);
        }
        __syncthreads();
    }
#pragma unroll
    for (int i = 0; i < 4; ++i) {
        int gr = mt + ty * 4 + i;
        if (gr < M)
            *(float4*)&C[(long long)gr * Nn + nt + tx * 4] =
                make_float4(acc[i][0], acc[i][1], acc[i][2], acc[i][3]);
    }
}

// -------------------- per-node attention scores ----------------------------
__global__ __launch_bounds__(256) void scores_k(const float* __restrict__ hmat,
                                                const float* __restrict__ asrc,
                                                const float* __restrict__ adst,
                                                long long N,
                                                float* __restrict__ esrc,
                                                float* __restrict__ edst) {
    long long n = blockIdx.x;
    if (n >= N) return;
    int t = threadIdx.x;
    float v  = hmat[n * HC + t];
    float ps = v * asrc[t];
    float pd = v * adst[t];
#pragma unroll
    for (int k = 32; k >= 1; k >>= 1) {
        ps += __shfl_xor(ps, k);
        pd += __shfl_xor(pd, k);
    }
    if ((t & 63) == 0) {
        int head = t >> 6;
        esrc[n * NH + head] = ps;
        edst[n * NH + head] = pd;
    }
}

// -------------------- softmax denominator ----------------------------------
__global__ __launch_bounds__(256) void denom_k(const int* __restrict__ ei,
                                               const int* __restrict__ flag,
                                               long long E, long long ET,
                                               const float* __restrict__ esrc,
                                               const float* __restrict__ edst,
                                               float* __restrict__ denom) {
    long long e = blockIdx.x * 256LL + threadIdx.x;
    if (e >= ET) return;
    int s, d;
    load_edge(ei, flag[0], E, e, s, d);
    float4 a = *(const float4*)&esrc[(long long)s * NH];
    float4 b = *(const float4*)&edst[(long long)d * NH];
    float t0 = a.x + b.x, t1 = a.y + b.y, t2 = a.z + b.z, t3 = a.w + b.w;
    float* dn = &denom[(long long)d * NH];
    atomicAdd(dn + 0, __expf(t0 >= 0.f ? t0 : LRELU_SLOPE * t0));
    atomicAdd(dn + 1, __expf(t1 >= 0.f ? t1 : LRELU_SLOPE * t1));
    atomicAdd(dn + 2, __expf(t2 >= 0.f ? t2 : LRELU_SLOPE * t2));
    atomicAdd(dn + 3, __expf(t3 >= 0.f ? t3 : LRELU_SLOPE * t3));
}

// -------------------- layer1: concat aggregation ---------------------------
// one wave per edge; lane l owns cols [4l, 4l+4) of the 256-wide output row
__global__ __launch_bounds__(256) void aggregate_concat_k(const int* __restrict__ ei,
                                                          const int* __restrict__ flag,
                                                          long long E, long long ET,
                                                          const float* __restrict__ esrc,
                                                          const float* __restrict__ edst,
                                                          const float* __restrict__ denom,
                                                          const float* __restrict__ hsrc,
                                                          float* __restrict__ out) {
    long long wid = blockIdx.x * 4LL + (threadIdx.x >> 6);
    int lane = threadIdx.x & 63;
    if (wid >= ET) return;
    int s, d;
    load_edge(ei, flag[0], E, wid, s, d);
    int head = lane >> 4;
    float alpha = edge_alpha(esrc, edst, denom, s, d, head);
    float4 hv = *(const float4*)&hsrc[(long long)s * HC + lane * 4];
    float* ob = &out[(long long)d * HC + lane * 4];
    atomicAdd(ob + 0, alpha * hv.x);
    atomicAdd(ob + 1, alpha * hv.y);
    atomicAdd(ob + 2, alpha * hv.z);
    atomicAdd(ob + 3, alpha * hv.w);
}

// -------------------- layer2: head-mean aggregation (fused) ----------------
// one wave per edge; lane l -> head l>>4, within-head col base (4l)&63
__global__ __launch_bounds__(256) void aggregate_mean_k(const int* __restrict__ ei,
                                                        const int* __restrict__ flag,
                                                        long long E, long long ET,
                                                        const float* __restrict__ esrc,
                                                        const float* __restrict__ edst,
                                                        const float* __restrict__ denom,
                                                        const float* __restrict__ hsrc,
                                                        float* __restrict__ outhalf) {
    long long wid = blockIdx.x * 4LL + (threadIdx.x >> 6);
    int lane = threadIdx.x & 63;
    if (wid >= ET) return;
    int s, d;
    load_edge(ei, flag[0], E, wid, s, d);
    int head = lane >> 4;
    float alpha = 0.25f * edge_alpha(esrc, edst, denom, s, d, head);
    float4 hv = *(const float4*)&hsrc[(long long)s * HC + lane * 4];
    int col = (lane * 4) & 63;
    float* ob = &outhalf[(long long)d * 64 + col];
    atomicAdd(ob + 0, alpha * hv.x);
    atomicAdd(ob + 1, alpha * hv.y);
    atomicAdd(ob + 2, alpha * hv.z);
    atomicAdd(ob + 3, alpha * hv.w);
}

// -------------------- init output half with bias ---------------------------
__global__ __launch_bounds__(256) void init_out_k(float* __restrict__ outhalf,
                                                  const float* __restrict__ bias,
                                                  long long count) {
    long long i = blockIdx.x * 256LL + threadIdx.x;
    if (i < count) outhalf[i] = bias[i & 63];
}

// -------------------- batchnorm stats (sum, sumsq per column) --------------
__global__ __launch_bounds__(256) void bn_stats_k(const float* __restrict__ x,
                                                  const float* __restrict__ b1,
                                                  long long N, float* __restrict__ sums) {
    int c = threadIdx.x;
    long long r0 = (long long)blockIdx.x * 256;
    long long r1 = r0 + 256 < N ? r0 + 256 : N;
    float bias = b1[c];
    float s = 0.f, ss = 0.f;
    for (long long r = r0; r < r1; ++r) {
        float v = x[r * HC + c] + bias;
        s += v; ss += v * v;
    }
    atomicAdd(&sums[c], s);
    atomicAdd(&sums[HC + c], ss);
}

__global__ __launch_bounds__(256) void bn_norm_relu_k(const float* __restrict__ x,
                                                      const float* __restrict__ b1,
                                                      const float* __restrict__ sums,
                                                      const float* __restrict__ gamma,
                                                      const float* __restrict__ beta,
                                                      long long N, float* __restrict__ out) {
    long long i = blockIdx.x * 256LL + threadIdx.x;
    if (i >= N * HC) return;
    int c = (int)(i & (HC - 1));
    float invN = 1.0f / (float)N;
    float mu  = sums[c] * invN;
    float var = sums[HC + c] * invN - mu * mu;
    float v = (x[i] + b1[c] - mu) * rsqrtf(var + BN_EPS) * gamma[c] + beta[c];
    out[i] = v > 0.f ? v : 0.f;
}

// ---------------------------------------------------------------------------
extern "C" void kernel_launch(void* const* d_in, const int* in_sizes, int n_in,
                              void* d_out, int out_size, void* d_ws, size_t ws_size,
                              hipStream_t stream) {
    const float* x      = (const float*)d_in[0];
    const int*   ei     = (const int*)d_in[1];
    const float* W1     = (const float*)d_in[2];
    const float* a_src1 = (const float*)d_in[3];
    const float* a_dst1 = (const float*)d_in[4];
    const float* b1     = (const float*)d_in[5];
    const float* gamma1 = (const float*)d_in[6];
    const float* beta1  = (const float*)d_in[7];
    const float* Wm     = (const float*)d_in[8];
    const float* am_src = (const float*)d_in[9];
    const float* am_dst = (const float*)d_in[10];
    const float* bm     = (const float*)d_in[11];
    const float* Ws     = (const float*)d_in[12];
    const float* as_src = (const float*)d_in[13];
    const float* as_dst = (const float*)d_in[14];
    const float* bs     = (const float*)d_in[15];
    float* out = (float*)d_out;

    const long long N  = in_sizes[0] / 256;   // 50000
    const long long E  = in_sizes[1] / 2;     // 800000
    const long long ET = E + N;               // with self loops

    // ---- workspace layout (256B aligned bump allocator), ~105MB total ----
    size_t off = 0;
    auto alloc = [&](size_t bytes) -> char* {
        size_t o = off;
        off += (bytes + 255) & ~(size_t)255;
        return (char*)d_ws + o;
    };
    int*   flag  = (int*)  alloc(256);
    float* sums  = (float*)alloc(2 * HC * sizeof(float));
    float* es    = (float*)alloc(N * NH * sizeof(float));
    float* ed    = (float*)alloc(N * NH * sizeof(float));
    float* denom = (float*)alloc(N * NH * sizeof(float));
    float* B1    = (float*)alloc(N * HC * sizeof(float));   // h1, then h
    float* B2    = (float*)alloc(N * HC * sizeof(float));   // agg1, then hm, then hs
    (void)ws_size; (void)n_in; (void)out_size;

    const int M = (int)N;
    dim3 ggrid(HC / GTN, (M + GTM - 1) / GTM);
    const long long egrid = (ET + 255) / 256;   // 1 thread / edge
    const long long agrid = (ET + 3) / 4;       // 1 wave / edge
    const long long ngrid = (N * HC + 255) / 256;
    const long long sgrid = (N + 255) / 256;
    const long long fgrid = (N * 64 + 255) / 256;

    detect_k<<<1, 256, 0, stream>>>(ei, E, flag);

    // ---- layer 1 (concat) ----
    gemm_k<<<ggrid, 256, 0, stream>>>(x, W1, B1, M, HC, 256);
    scores_k<<<(int)N, 256, 0, stream>>>(B1, a_src1, a_dst1, N, es, ed);
    hipMemsetAsync(denom, 0, N * NH * sizeof(float), stream);
    denom_k<<<(int)egrid, 256, 0, stream>>>(ei, flag, E, ET, es, ed, denom);
    hipMemsetAsync(B2, 0, N * HC * sizeof(float), stream);
    aggregate_concat_k<<<(int)agrid, 256, 0, stream>>>(ei, flag, E, ET, es, ed, denom, B1, B2);
    hipMemsetAsync(sums, 0, 2 * HC * sizeof(float), stream);
    bn_stats_k<<<(int)sgrid, 256, 0, stream>>>(B2, b1, N, sums);
    bn_norm_relu_k<<<(int)ngrid, 256, 0, stream>>>(B2, b1, sums, gamma1, beta1, N, B1);

    // ---- layer 2, mean branch ----
    gemm_k<<<ggrid, 256, 0, stream>>>(B1, Wm, B2, M, HC, 256);
    scores_k<<<(int)N, 256, 0, stream>>>(B2, am_src, am_dst, N, es, ed);
    hipMemsetAsync(denom, 0, N * NH * sizeof(float), stream);
    denom_k<<<(int)egrid, 256, 0, stream>>>(ei, flag, E, ET, es, ed, denom);
    init_out_k<<<(int)fgrid, 256, 0, stream>>>(out, bm, N * 64);
    aggregate_mean_k<<<(int)agrid, 256, 0, stream>>>(ei, flag, E, ET, es, ed, denom, B2, out);

    // ---- layer 2, log_std branch ----
    gemm_k<<<ggrid, 256, 0, stream>>>(B1, Ws, B2, M, HC, 256);
    scores_k<<<(int)N, 256, 0, stream>>>(B2, as_src, as_dst, N, es, ed);
    hipMemsetAsync(denom, 0, N * NH * sizeof(float), stream);
    denom_k<<<(int)egrid, 256, 0, stream>>>(ei, flag, E, ET, es, ed, denom);
    init_out_k<<<(int)fgrid, 256, 0, stream>>>(out + N * 64, bs, N * 64);
    aggregate_mean_k<<<(int)agrid, 256, 0, stream>>>(ei, flag, E, ET, es, ed, denom, B2, out + N * 64);
}

// Round 3
// 1068.069 us; speedup vs baseline: 10.3128x; 10.3128x over previous
//
#include <hip/hip_runtime.h>
#include <hip/hip_bf16.h>

// ---------------------------------------------------------------------------
// GAT encoder: 2x GATConv + BatchNorm/ReLU. N=50000, E=800000(+N self loops),
// Fin=256, H=4, C=64, L=64. All fp32.
// Round 3: CSR-by-dst built on device; aggregation is a gather (one wave per
// dst node) that accumulates numerator AND softmax denominator in registers
// and writes each output row exactly once. Zero atomics in the hot path.
// ---------------------------------------------------------------------------

#define HC 256   // H*C
#define NH 4     // heads
#define LRELU_SLOPE 0.2f
#define BN_EPS 1e-5f

// -------------------- edge-index dtype detection (int32 vs int64) ----------
__global__ void detect_k(const int* __restrict__ ei, long long E, int* __restrict__ flag) {
    __shared__ int any;
    if (threadIdx.x == 0) any = 0;
    __syncthreads();
    for (int i = threadIdx.x; i < 1024; i += blockDim.x) {
        long long idx = 2LL * i + 1;                 // hi-word position if int64
        if (idx < 2 * E && ei[idx] != 0) atomicOr(&any, 1);
    }
    __syncthreads();
    if (threadIdx.x == 0) flag[0] = (any == 0) ? 1 : 0;   // 1 => int64 layout
}

__device__ __forceinline__ void load_edge(const int* __restrict__ ei, int flag64,
                                          long long E, long long e, int& s, int& d) {
    if (e >= E) { s = d = (int)(e - E); return; }        // appended self-loops
    if (flag64) { s = ei[2 * e]; d = ei[2 * E + 2 * e]; }
    else        { s = ei[e];     d = ei[E + e]; }
}

// -------------------- CSR build: histogram -> scan -> scatter ---------------
__global__ __launch_bounds__(256) void hist_k(const int* __restrict__ ei,
                                              const int* __restrict__ flag,
                                              long long E, long long ET,
                                              int* __restrict__ deg) {
    long long e = blockIdx.x * 256LL + threadIdx.x;
    if (e >= ET) return;
    int s, d;
    load_edge(ei, flag[0], E, e, s, d);
    atomicAdd(&deg[d], 1);
}

// per-block exclusive scan; block sums out
__global__ __launch_bounds__(256) void scan1_k(const int* __restrict__ deg,
                                               int* __restrict__ excl,
                                               int* __restrict__ bsum, long long N) {
    __shared__ int buf[256];
    long long i = blockIdx.x * 256LL + threadIdx.x;
    int v = (i < N) ? deg[i] : 0;
    buf[threadIdx.x] = v;
    __syncthreads();
#pragma unroll
    for (int o = 1; o < 256; o <<= 1) {
        int t = (threadIdx.x >= o) ? buf[threadIdx.x - o] : 0;
        __syncthreads();
        buf[threadIdx.x] += t;
        __syncthreads();
    }
    if (i < N) excl[i] = buf[threadIdx.x] - v;
    if (threadIdx.x == 255) bsum[blockIdx.x] = buf[255];
}

// single-block exclusive scan of block sums (nb <= 256)
__global__ __launch_bounds__(256) void scan2_k(int* __restrict__ bsum, int nb) {
    __shared__ int buf[256];
    int v = (threadIdx.x < nb) ? bsum[threadIdx.x] : 0;
    buf[threadIdx.x] = v;
    __syncthreads();
#pragma unroll
    for (int o = 1; o < 256; o <<= 1) {
        int t = (threadIdx.x >= o) ? buf[threadIdx.x - o] : 0;
        __syncthreads();
        buf[threadIdx.x] += t;
        __syncthreads();
    }
    if (threadIdx.x < nb) bsum[threadIdx.x] = buf[threadIdx.x] - v;
}

__global__ __launch_bounds__(256) void scan3_k(int* __restrict__ rowptr,
                                               const int* __restrict__ bsum,
                                               long long N, long long ET) {
    long long i = blockIdx.x * 256LL + threadIdx.x;
    if (i < N) rowptr[i] += bsum[blockIdx.x];
    if (i == N) rowptr[N] = (int)ET;
}

__global__ __launch_bounds__(256) void scatter_k(const int* __restrict__ ei,
                                                 const int* __restrict__ flag,
                                                 long long E, long long ET,
                                                 const int* __restrict__ rowptr,
                                                 int* __restrict__ cursor,
                                                 int* __restrict__ csr_src) {
    long long e = blockIdx.x * 256LL + threadIdx.x;
    if (e >= ET) return;
    int s, d;
    load_edge(ei, flag[0], E, e, s, d);
    int pos = rowptr[d] + atomicAdd(&cursor[d], 1);
    csr_src[pos] = s;
}

// -------------------- tiled fp32 GEMM: C[M,Nn] = A[M,K] @ B[K,Nn] ----------
#define GTM 64
#define GTN 64
#define GTK 16
__global__ __launch_bounds__(256) void gemm_k(const float* __restrict__ A,
                                              const float* __restrict__ B,
                                              float* __restrict__ C,
                                              int M, int Nn, int K) {
    __shared__ float As[GTM][GTK + 1];
    __shared__ float Bs[GTK][GTN + 1];
    const int mt = blockIdx.y * GTM;
    const int nt = blockIdx.x * GTN;
    const int t  = threadIdx.x;
    const int tx = t & 15, ty = t >> 4;
    float acc[4][4] = {};
    for (int k0 = 0; k0 < K; k0 += GTK) {
        {   // A tile: 64x16, one float4 per thread
            int r = t >> 2, c = (t & 3) * 4;
            int gr = mt + r;
            float4 v = (gr < M) ? *(const float4*)&A[(long long)gr * K + k0 + c]
                                : make_float4(0.f, 0.f, 0.f, 0.f);
            As[r][c] = v.x; As[r][c + 1] = v.y; As[r][c + 2] = v.z; As[r][c + 3] = v.w;
        }
        {   // B tile: 16x64, one float4 per thread
            int r = t >> 4, c = (t & 15) * 4;
            float4 v = *(const float4*)&B[(long long)(k0 + r) * Nn + nt + c];
            Bs[r][c] = v.x; Bs[r][c + 1] = v.y; Bs[r][c + 2] = v.z; Bs[r][c + 3] = v.w;
        }
        __syncthreads();
#pragma unroll
        for (int kk = 0; kk < GTK; ++kk) {
            float a[4], b[4];
#pragma unroll
            for (int i = 0; i < 4; ++i) a[i] = As[ty * 4 + i][kk];
#pragma unroll
            for (int j = 0; j < 4; ++j) b[j] = Bs[kk][tx * 4 + j];
#pragma unroll
            for (int i = 0; i < 4; ++i)
#pragma unroll
                for (int j = 0; j < 4; ++j) acc[i][j] = fmaf(a[i], b[j], acc[i][j]);
        }
        __syncthreads();
    }
#pragma unroll
    for (int i = 0; i < 4; ++i) {
        int gr = mt + ty * 4 + i;
        if (gr < M)
            *(float4*)&C[(long long)gr * Nn + nt + tx * 4] =
                make_float4(acc[i][0], acc[i][1], acc[i][2], acc[i][3]);
    }
}

// -------------------- per-node attention scores ----------------------------
__global__ __launch_bounds__(256) void scores_k(const float* __restrict__ hmat,
                                                const float* __restrict__ asrc,
                                                const float* __restrict__ adst,
                                                long long N,
                                                float* __restrict__ esrc,
                                                float* __restrict__ edst) {
    long long n = blockIdx.x;
    if (n >= N) return;
    int t = threadIdx.x;
    float v  = hmat[n * HC + t];
    float ps = v * asrc[t];
    float pd = v * adst[t];
#pragma unroll
    for (int k = 32; k >= 1; k >>= 1) {
        ps += __shfl_xor(ps, k);
        pd += __shfl_xor(pd, k);
    }
    if ((t & 63) == 0) {
        int head = t >> 6;
        esrc[n * NH + head] = ps;
        edst[n * NH + head] = pd;
    }
}

// -------------------- CSR gather aggregation, concat (layer 1) -------------
// one wave per dst node; lane l owns cols [4l,4l+4), head = l>>4.
// accumulates numerator and softmax denominator together; writes row once.
__global__ __launch_bounds__(256) void agg_concat_k(const int* __restrict__ rowptr,
                                                    const int* __restrict__ csr_src,
                                                    const float* __restrict__ esrc,
                                                    const float* __restrict__ edst,
                                                    const float* __restrict__ h,
                                                    long long N,
                                                    float* __restrict__ out) {
    long long d = blockIdx.x * 4LL + (threadIdx.x >> 6);
    if (d >= N) return;
    int lane = threadIdx.x & 63;
    int head = lane >> 4;
    float edv = edst[d * NH + head];
    int beg = rowptr[d], end = rowptr[d + 1];
    float a0 = 0.f, a1 = 0.f, a2 = 0.f, a3 = 0.f, den = 0.f;
    for (int i = beg; i < end; ++i) {
        int s = csr_src[i];
        float t = esrc[(long long)s * NH + head] + edv;
        t = t >= 0.f ? t : LRELU_SLOPE * t;
        float w = __expf(t);
        den += w;
        float4 hv = *(const float4*)&h[(long long)s * HC + lane * 4];
        a0 = fmaf(w, hv.x, a0); a1 = fmaf(w, hv.y, a1);
        a2 = fmaf(w, hv.z, a2); a3 = fmaf(w, hv.w, a3);
    }
    float inv = 1.0f / den;   // den > 0: self-loop guarantees >= 1 edge
    *(float4*)&out[d * HC + lane * 4] = make_float4(a0 * inv, a1 * inv, a2 * inv, a3 * inv);
}

// -------------------- CSR gather aggregation, head-mean (layer 2) ----------
// same walk; per-head normalize, then cross-head butterfly (lanes ^16, ^32),
// lanes 0..15 write the 64-wide row with bias fused.
__global__ __launch_bounds__(256) void agg_mean_k(const int* __restrict__ rowptr,
                                                  const int* __restrict__ csr_src,
                                                  const float* __restrict__ esrc,
                                                  const float* __restrict__ edst,
                                                  const float* __restrict__ h,
                                                  const float* __restrict__ bias,
                                                  long long N,
                                                  float* __restrict__ outhalf) {
    long long d = blockIdx.x * 4LL + (threadIdx.x >> 6);
    if (d >= N) return;
    int lane = threadIdx.x & 63;
    int head = lane >> 4;
    float edv = edst[d * NH + head];
    int beg = rowptr[d], end = rowptr[d + 1];
    float a0 = 0.f, a1 = 0.f, a2 = 0.f, a3 = 0.f, den = 0.f;
    for (int i = beg; i < end; ++i) {
        int s = csr_src[i];
        float t = esrc[(long long)s * NH + head] + edv;
        t = t >= 0.f ? t : LRELU_SLOPE * t;
        float w = __expf(t);
        den += w;
        float4 hv = *(const float4*)&h[(long long)s * HC + lane * 4];
        a0 = fmaf(w, hv.x, a0); a1 = fmaf(w, hv.y, a1);
        a2 = fmaf(w, hv.z, a2); a3 = fmaf(w, hv.w, a3);
    }
    float inv = 1.0f / den;
    a0 *= inv; a1 *= inv; a2 *= inv; a3 *= inv;
    // sum the 4 heads: lanes l, l^16, l^32, l^48 hold the same within-head col
    a0 += __shfl_xor(a0, 16); a0 += __shfl_xor(a0, 32);
    a1 += __shfl_xor(a1, 16); a1 += __shfl_xor(a1, 32);
    a2 += __shfl_xor(a2, 16); a2 += __shfl_xor(a2, 32);
    a3 += __shfl_xor(a3, 16); a3 += __shfl_xor(a3, 32);
    if (lane < 16) {
        int cb = lane * 4;
        *(float4*)&outhalf[d * 64 + cb] =
            make_float4(0.25f * a0 + bias[cb],     0.25f * a1 + bias[cb + 1],
                        0.25f * a2 + bias[cb + 2], 0.25f * a3 + bias[cb + 3]);
    }
}

// -------------------- batchnorm stats (sum, sumsq per column) --------------
__global__ __launch_bounds__(256) void bn_stats_k(const float* __restrict__ x,
                                                  const float* __restrict__ b1,
                                                  long long N, float* __restrict__ sums) {
    int c = threadIdx.x;
    long long r0 = (long long)blockIdx.x * 256;
    long long r1 = r0 + 256 < N ? r0 + 256 : N;
    float bias = b1[c];
    float s = 0.f, ss = 0.f;
    for (long long r = r0; r < r1; ++r) {
        float v = x[r * HC + c] + bias;
        s += v; ss += v * v;
    }
    atomicAdd(&sums[c], s);
    atomicAdd(&sums[HC + c], ss);
}

__global__ __launch_bounds__(256) void bn_norm_relu_k(const float* __restrict__ x,
                                                      const float* __restrict__ b1,
                                                      const float* __restrict__ sums,
                                                      const float* __restrict__ gamma,
                                                      const float* __restrict__ beta,
                                                      long long N, float* __restrict__ out) {
    long long i = blockIdx.x * 256LL + threadIdx.x;
    if (i >= N * HC) return;
    int c = (int)(i & (HC - 1));
    float invN = 1.0f / (float)N;
    float mu  = sums[c] * invN;
    float var = sums[HC + c] * invN - mu * mu;
    float v = (x[i] + b1[c] - mu) * rsqrtf(var + BN_EPS) * gamma[c] + beta[c];
    out[i] = v > 0.f ? v : 0.f;
}

// ---------------------------------------------------------------------------
extern "C" void kernel_launch(void* const* d_in, const int* in_sizes, int n_in,
                              void* d_out, int out_size, void* d_ws, size_t ws_size,
                              hipStream_t stream) {
    const float* x      = (const float*)d_in[0];
    const int*   ei     = (const int*)d_in[1];
    const float* W1     = (const float*)d_in[2];
    const float* a_src1 = (const float*)d_in[3];
    const float* a_dst1 = (const float*)d_in[4];
    const float* b1     = (const float*)d_in[5];
    const float* gamma1 = (const float*)d_in[6];
    const float* beta1  = (const float*)d_in[7];
    const float* Wm     = (const float*)d_in[8];
    const float* am_src = (const float*)d_in[9];
    const float* am_dst = (const float*)d_in[10];
    const float* bm     = (const float*)d_in[11];
    const float* Ws     = (const float*)d_in[12];
    const float* as_src = (const float*)d_in[13];
    const float* as_dst = (const float*)d_in[14];
    const float* bs     = (const float*)d_in[15];
    float* out = (float*)d_out;

    const long long N  = in_sizes[0] / 256;   // 50000
    const long long E  = in_sizes[1] / 2;     // 800000
    const long long ET = E + N;               // with self loops
    const int nb = (int)((N + 255) / 256);    // scan blocks (196 <= 256)

    // ---- workspace layout (256B aligned bump allocator), ~108MB total ----
    size_t off = 0;
    auto alloc = [&](size_t bytes) -> char* {
        size_t o = off;
        off += (bytes + 255) & ~(size_t)255;
        return (char*)d_ws + o;
    };
    int*   flag    = (int*)  alloc(256);
    float* sums    = (float*)alloc(2 * HC * sizeof(float));
    int*   bsum    = (int*)  alloc(256 * sizeof(int));
    float* es      = (float*)alloc(N * NH * sizeof(float));
    float* ed      = (float*)alloc(N * NH * sizeof(float));
    int*   deg     = (int*)  alloc(N * sizeof(int));        // reused as cursor
    int*   rowptr  = (int*)  alloc((N + 1) * sizeof(int));
    int*   csr_src = (int*)  alloc(ET * sizeof(int));
    float* B1      = (float*)alloc(N * HC * sizeof(float)); // h1, then h
    float* B2      = (float*)alloc(N * HC * sizeof(float)); // agg1, then hm, then hs
    (void)ws_size; (void)n_in; (void)out_size;

    const int M = (int)N;
    dim3 ggrid(HC / GTN, (M + GTM - 1) / GTM);
    const long long egrid = (ET + 255) / 256;   // 1 thread / edge
    const long long agrid = (N + 3) / 4;        // 1 wave / dst node
    const long long ngrid = (N * HC + 255) / 256;

    detect_k<<<1, 256, 0, stream>>>(ei, E, flag);

    // ---- CSR by destination (built once, reused by all 3 aggregations) ----
    hipMemsetAsync(deg, 0, N * sizeof(int), stream);
    hist_k<<<(int)egrid, 256, 0, stream>>>(ei, flag, E, ET, deg);
    scan1_k<<<nb, 256, 0, stream>>>(deg, rowptr, bsum, N);
    scan2_k<<<1, 256, 0, stream>>>(bsum, nb);
    scan3_k<<<nb + 1, 256, 0, stream>>>(rowptr, bsum, N, ET);
    hipMemsetAsync(deg, 0, N * sizeof(int), stream);        // cursor
    scatter_k<<<(int)egrid, 256, 0, stream>>>(ei, flag, E, ET, rowptr, deg, csr_src);

    // ---- layer 1 (concat) ----
    gemm_k<<<ggrid, 256, 0, stream>>>(x, W1, B1, M, HC, 256);
    scores_k<<<(int)N, 256, 0, stream>>>(B1, a_src1, a_dst1, N, es, ed);
    agg_concat_k<<<(int)agrid, 256, 0, stream>>>(rowptr, csr_src, es, ed, B1, N, B2);
    hipMemsetAsync(sums, 0, 2 * HC * sizeof(float), stream);
    bn_stats_k<<<nb, 256, 0, stream>>>(B2, b1, N, sums);
    bn_norm_relu_k<<<(int)ngrid, 256, 0, stream>>>(B2, b1, sums, gamma1, beta1, N, B1);

    // ---- layer 2, mean branch ----
    gemm_k<<<ggrid, 256, 0, stream>>>(B1, Wm, B2, M, HC, 256);
    scores_k<<<(int)N, 256, 0, stream>>>(B2, am_src, am_dst, N, es, ed);
    agg_mean_k<<<(int)agrid, 256, 0, stream>>>(rowptr, csr_src, es, ed, B2, bm, N, out);

    // ---- layer 2, log_std branch ----
    gemm_k<<<ggrid, 256, 0, stream>>>(B1, Ws, B2, M, HC, 256);
    scores_k<<<(int)N, 256, 0, stream>>>(B2, as_src, as_dst, N, es, ed);
    agg_mean_k<<<(int)agrid, 256, 0, stream>>>(rowptr, csr_src, es, ed, B2, bs, N, out + N * 64);
}

// Round 4
// 918.085 us; speedup vs baseline: 11.9976x; 1.1634x over previous
//
#include <hip/hip_runtime.h>
#include <hip/hip_bf16.h>

// ---------------------------------------------------------------------------
// GAT encoder: 2x GATConv + BatchNorm/ReLU. N=50000, E=800000(+N self loops),
// Fin=256, H=4, C=64, L=64.
// Round 4: GEMMs on matrix cores via split-bf16 (hi+lo) 3-term MFMA with fp32
// accumulate -> fp32-grade accuracy at ~MFMA speed. LDS-free, barrier-free
// register GEMM: wave = 32 rows x 128 cols, B (weights) pre-transposed to
// bf16 hi/lo [n][k] (L2-resident). CSR gather aggregation unchanged.
// ---------------------------------------------------------------------------

#define HC 256   // H*C
#define NH 4     // heads
#define LRELU_SLOPE 0.2f
#define BN_EPS 1e-5f

typedef __attribute__((ext_vector_type(8))) short bf16x8_t;
typedef __attribute__((ext_vector_type(4))) float f32x4_t;

__device__ __forceinline__ unsigned short f2bf(float f) {   // RNE
    unsigned u = __float_as_uint(f);
    u += 0x7fffu + ((u >> 16) & 1u);
    return (unsigned short)(u >> 16);
}
__device__ __forceinline__ float bf2f(unsigned short h) {
    return __uint_as_float(((unsigned)h) << 16);
}

// -------------------- edge-index dtype detection (int32 vs int64) ----------
__global__ void detect_k(const int* __restrict__ ei, long long E, int* __restrict__ flag) {
    __shared__ int any;
    if (threadIdx.x == 0) any = 0;
    __syncthreads();
    for (int i = threadIdx.x; i < 1024; i += blockDim.x) {
        long long idx = 2LL * i + 1;                 // hi-word position if int64
        if (idx < 2 * E && ei[idx] != 0) atomicOr(&any, 1);
    }
    __syncthreads();
    if (threadIdx.x == 0) flag[0] = (any == 0) ? 1 : 0;   // 1 => int64 layout
}

__device__ __forceinline__ void load_edge(const int* __restrict__ ei, int flag64,
                                          long long E, long long e, int& s, int& d) {
    if (e >= E) { s = d = (int)(e - E); return; }        // appended self-loops
    if (flag64) { s = ei[2 * e]; d = ei[2 * E + 2 * e]; }
    else        { s = ei[e];     d = ei[E + e]; }
}

// -------------------- CSR build: histogram -> scan -> scatter ---------------
__global__ __launch_bounds__(256) void hist_k(const int* __restrict__ ei,
                                              const int* __restrict__ flag,
                                              long long E, long long ET,
                                              int* __restrict__ deg) {
    long long e = blockIdx.x * 256LL + threadIdx.x;
    if (e >= ET) return;
    int s, d;
    load_edge(ei, flag[0], E, e, s, d);
    atomicAdd(&deg[d], 1);
}

__global__ __launch_bounds__(256) void scan1_k(const int* __restrict__ deg,
                                               int* __restrict__ excl,
                                               int* __restrict__ bsum, long long N) {
    __shared__ int buf[256];
    long long i = blockIdx.x * 256LL + threadIdx.x;
    int v = (i < N) ? deg[i] : 0;
    buf[threadIdx.x] = v;
    __syncthreads();
#pragma unroll
    for (int o = 1; o < 256; o <<= 1) {
        int t = (threadIdx.x >= o) ? buf[threadIdx.x - o] : 0;
        __syncthreads();
        buf[threadIdx.x] += t;
        __syncthreads();
    }
    if (i < N) excl[i] = buf[threadIdx.x] - v;
    if (threadIdx.x == 255) bsum[blockIdx.x] = buf[255];
}

__global__ __launch_bounds__(256) void scan2_k(int* __restrict__ bsum, int nb) {
    __shared__ int buf[256];
    int v = (threadIdx.x < nb) ? bsum[threadIdx.x] : 0;
    buf[threadIdx.x] = v;
    __syncthreads();
#pragma unroll
    for (int o = 1; o < 256; o <<= 1) {
        int t = (threadIdx.x >= o) ? buf[threadIdx.x - o] : 0;
        __syncthreads();
        buf[threadIdx.x] += t;
        __syncthreads();
    }
    if (threadIdx.x < nb) bsum[threadIdx.x] = buf[threadIdx.x] - v;
}

__global__ __launch_bounds__(256) void scan3_k(int* __restrict__ rowptr,
                                               const int* __restrict__ bsum,
                                               long long N, long long ET) {
    long long i = blockIdx.x * 256LL + threadIdx.x;
    if (i < N) rowptr[i] += bsum[blockIdx.x];
    if (i == N) rowptr[N] = (int)ET;
}

__global__ __launch_bounds__(256) void scatter_k(const int* __restrict__ ei,
                                                 const int* __restrict__ flag,
                                                 long long E, long long ET,
                                                 const int* __restrict__ rowptr,
                                                 int* __restrict__ cursor,
                                                 int* __restrict__ csr_src) {
    long long e = blockIdx.x * 256LL + threadIdx.x;
    if (e >= ET) return;
    int s, d;
    load_edge(ei, flag[0], E, e, s, d);
    int pos = rowptr[d] + atomicAdd(&cursor[d], 1);
    csr_src[pos] = s;
}

// -------------------- weight transpose + split-bf16 convert ----------------
// T[n][k] = W[k][n]; hi = bf16(w), lo = bf16(w - hi). 256x256 each.
__global__ __launch_bounds__(256) void wconv_k(const float* __restrict__ W1,
                                               const float* __restrict__ Wm,
                                               const float* __restrict__ Ws,
                                               unsigned short* __restrict__ T1h,
                                               unsigned short* __restrict__ T1l,
                                               unsigned short* __restrict__ Tmh,
                                               unsigned short* __restrict__ Tml,
                                               unsigned short* __restrict__ Tsh,
                                               unsigned short* __restrict__ Tsl) {
    __shared__ float tile[32][33];
    const float* W = blockIdx.z == 0 ? W1 : (blockIdx.z == 1 ? Wm : Ws);
    unsigned short* Th = blockIdx.z == 0 ? T1h : (blockIdx.z == 1 ? Tmh : Tsh);
    unsigned short* Tl = blockIdx.z == 0 ? T1l : (blockIdx.z == 1 ? Tml : Tsl);
    int k0 = blockIdx.y * 32, n0 = blockIdx.x * 32;
    int tx = threadIdx.x & 31, ty = threadIdx.x >> 5;
    for (int r = ty; r < 32; r += 8)
        tile[r][tx] = W[(k0 + r) * 256 + n0 + tx];
    __syncthreads();
    for (int r = ty; r < 32; r += 8) {
        float v = tile[tx][r];
        unsigned short h = f2bf(v);
        Th[(n0 + r) * 256 + k0 + tx] = h;
        Tl[(n0 + r) * 256 + k0 + tx] = f2bf(v - bf2f(h));
    }
}

// -------------------- split-bf16 MFMA GEMM ---------------------------------
// C[M,256] = A[M,256] @ W, W given as Bt[n][k] bf16 hi/lo.
// One wave -> 32 rows x 128 cols. No LDS, no barriers.
__device__ __forceinline__ void cvt_frag(const float* p, bf16x8_t& hi, bf16x8_t& lo) {
    const float4 x0 = *(const float4*)p;
    const float4 x1 = *(const float4*)(p + 4);
    float v[8] = {x0.x, x0.y, x0.z, x0.w, x1.x, x1.y, x1.z, x1.w};
#pragma unroll
    for (int i = 0; i < 8; ++i) {
        unsigned short h = f2bf(v[i]);
        hi[i] = (short)h;
        lo[i] = (short)f2bf(v[i] - bf2f(h));
    }
}

__global__ __launch_bounds__(256) void gemm_mfma_k(const float* __restrict__ A,
                                                   const unsigned short* __restrict__ Bh,
                                                   const unsigned short* __restrict__ Bl,
                                                   float* __restrict__ C, int M) {
    const int warp = threadIdx.x >> 6;
    const int lane = threadIdx.x & 63;
    const int r0 = (blockIdx.x * 4 + warp) * 32;
    if (r0 >= M) return;
    const int nb = blockIdx.y * 128;
    const int q  = lane >> 4;       // k-group 0..3
    const int ln = lane & 15;
    int ra0 = r0 + ln;        if (ra0 >= M) ra0 = M - 1;
    int ra1 = r0 + 16 + ln;   if (ra1 >= M) ra1 = M - 1;
    const float* pa0 = A + (long long)ra0 * 256 + q * 8;
    const float* pa1 = A + (long long)ra1 * 256 + q * 8;
    const unsigned short* pbh = Bh + (long long)(nb + ln) * 256 + q * 8;
    const unsigned short* pbl = Bl + (long long)(nb + ln) * 256 + q * 8;

    f32x4_t acc0[8] = {}, acc1[8] = {};
#pragma unroll 2
    for (int ks = 0; ks < 8; ++ks) {           // K = 256 in steps of 32
        bf16x8_t a0h, a0l, a1h, a1l;
        cvt_frag(pa0, a0h, a0l);
        cvt_frag(pa1, a1h, a1l);
#pragma unroll
        for (int j = 0; j < 8; ++j) {          // col frags: n = nb + 16j + ln
            const bf16x8_t bh = *(const bf16x8_t*)(pbh + j * 4096);
            const bf16x8_t bl = *(const bf16x8_t*)(pbl + j * 4096);
            acc0[j] = __builtin_amdgcn_mfma_f32_16x16x32_bf16(a0h, bh, acc0[j], 0, 0, 0);
            acc0[j] = __builtin_amdgcn_mfma_f32_16x16x32_bf16(a0l, bh, acc0[j], 0, 0, 0);
            acc0[j] = __builtin_amdgcn_mfma_f32_16x16x32_bf16(a0h, bl, acc0[j], 0, 0, 0);
            acc1[j] = __builtin_amdgcn_mfma_f32_16x16x32_bf16(a1h, bh, acc1[j], 0, 0, 0);
            acc1[j] = __builtin_amdgcn_mfma_f32_16x16x32_bf16(a1l, bh, acc1[j], 0, 0, 0);
            acc1[j] = __builtin_amdgcn_mfma_f32_16x16x32_bf16(a1h, bl, acc1[j], 0, 0, 0);
        }
        pa0 += 32; pa1 += 32; pbh += 32; pbl += 32;
    }
    // D frag: lane holds rows q*4+i, col ln (within 16x16 tile)
#pragma unroll
    for (int j = 0; j < 8; ++j) {
        int col = nb + j * 16 + ln;
#pragma unroll
        for (int i = 0; i < 4; ++i) {
            int r = r0 + q * 4 + i;
            if (r < M) C[(long long)r * 256 + col] = acc0[j][i];
            r += 16;
            if (r < M) C[(long long)r * 256 + col] = acc1[j][i];
        }
    }
}

// -------------------- per-node attention scores ----------------------------
__global__ __launch_bounds__(256) void scores_k(const float* __restrict__ hmat,
                                                const float* __restrict__ asrc,
                                                const float* __restrict__ adst,
                                                long long N,
                                                float* __restrict__ esrc,
                                                float* __restrict__ edst) {
    long long n = blockIdx.x;
    if (n >= N) return;
    int t = threadIdx.x;
    float v  = hmat[n * HC + t];
    float ps = v * asrc[t];
    float pd = v * adst[t];
#pragma unroll
    for (int k = 32; k >= 1; k >>= 1) {
        ps += __shfl_xor(ps, k);
        pd += __shfl_xor(pd, k);
    }
    if ((t & 63) == 0) {
        int head = t >> 6;
        esrc[n * NH + head] = ps;
        edst[n * NH + head] = pd;
    }
}

// -------------------- CSR gather aggregation, concat (layer 1) -------------
__global__ __launch_bounds__(256) void agg_concat_k(const int* __restrict__ rowptr,
                                                    const int* __restrict__ csr_src,
                                                    const float* __restrict__ esrc,
                                                    const float* __restrict__ edst,
                                                    const float* __restrict__ h,
                                                    long long N,
                                                    float* __restrict__ out) {
    long long d = blockIdx.x * 4LL + (threadIdx.x >> 6);
    if (d >= N) return;
    int lane = threadIdx.x & 63;
    int head = lane >> 4;
    float edv = edst[d * NH + head];
    int beg = rowptr[d], end = rowptr[d + 1];
    float a0 = 0.f, a1 = 0.f, a2 = 0.f, a3 = 0.f, den = 0.f;
    for (int i = beg; i < end; ++i) {
        int s = csr_src[i];
        float t = esrc[(long long)s * NH + head] + edv;
        t = t >= 0.f ? t : LRELU_SLOPE * t;
        float w = __expf(t);
        den += w;
        float4 hv = *(const float4*)&h[(long long)s * HC + lane * 4];
        a0 = fmaf(w, hv.x, a0); a1 = fmaf(w, hv.y, a1);
        a2 = fmaf(w, hv.z, a2); a3 = fmaf(w, hv.w, a3);
    }
    float inv = 1.0f / den;
    *(float4*)&out[d * HC + lane * 4] = make_float4(a0 * inv, a1 * inv, a2 * inv, a3 * inv);
}

// -------------------- CSR gather aggregation, head-mean (layer 2) ----------
__global__ __launch_bounds__(256) void agg_mean_k(const int* __restrict__ rowptr,
                                                  const int* __restrict__ csr_src,
                                                  const float* __restrict__ esrc,
                                                  const float* __restrict__ edst,
                                                  const float* __restrict__ h,
                                                  const float* __restrict__ bias,
                                                  long long N,
                                                  float* __restrict__ outhalf) {
    long long d = blockIdx.x * 4LL + (threadIdx.x >> 6);
    if (d >= N) return;
    int lane = threadIdx.x & 63;
    int head = lane >> 4;
    float edv = edst[d * NH + head];
    int beg = rowptr[d], end = rowptr[d + 1];
    float a0 = 0.f, a1 = 0.f, a2 = 0.f, a3 = 0.f, den = 0.f;
    for (int i = beg; i < end; ++i) {
        int s = csr_src[i];
        float t = esrc[(long long)s * NH + head] + edv;
        t = t >= 0.f ? t : LRELU_SLOPE * t;
        float w = __expf(t);
        den += w;
        float4 hv = *(const float4*)&h[(long long)s * HC + lane * 4];
        a0 = fmaf(w, hv.x, a0); a1 = fmaf(w, hv.y, a1);
        a2 = fmaf(w, hv.z, a2); a3 = fmaf(w, hv.w, a3);
    }
    float inv = 1.0f / den;
    a0 *= inv; a1 *= inv; a2 *= inv; a3 *= inv;
    a0 += __shfl_xor(a0, 16); a0 += __shfl_xor(a0, 32);
    a1 += __shfl_xor(a1, 16); a1 += __shfl_xor(a1, 32);
    a2 += __shfl_xor(a2, 16); a2 += __shfl_xor(a2, 32);
    a3 += __shfl_xor(a3, 16); a3 += __shfl_xor(a3, 32);
    if (lane < 16) {
        int cb = lane * 4;
        *(float4*)&outhalf[d * 64 + cb] =
            make_float4(0.25f * a0 + bias[cb],     0.25f * a1 + bias[cb + 1],
                        0.25f * a2 + bias[cb + 2], 0.25f * a3 + bias[cb + 3]);
    }
}

// -------------------- batchnorm ---------------------------------------------
__global__ __launch_bounds__(256) void bn_stats_k(const float* __restrict__ x,
                                                  const float* __restrict__ b1,
                                                  long long N, float* __restrict__ sums) {
    int c = threadIdx.x;
    long long r0 = (long long)blockIdx.x * 256;
    long long r1 = r0 + 256 < N ? r0 + 256 : N;
    float bias = b1[c];
    float s = 0.f, ss = 0.f;
    for (long long r = r0; r < r1; ++r) {
        float v = x[r * HC + c] + bias;
        s += v; ss += v * v;
    }
    atomicAdd(&sums[c], s);
    atomicAdd(&sums[HC + c], ss);
}

__global__ __launch_bounds__(256) void bn_norm_relu_k(const float* __restrict__ x,
                                                      const float* __restrict__ b1,
                                                      const float* __restrict__ sums,
                                                      const float* __restrict__ gamma,
                                                      const float* __restrict__ beta,
                                                      long long N, float* __restrict__ out) {
    long long i = blockIdx.x * 256LL + threadIdx.x;
    if (i >= N * HC) return;
    int c = (int)(i & (HC - 1));
    float invN = 1.0f / (float)N;
    float mu  = sums[c] * invN;
    float var = sums[HC + c] * invN - mu * mu;
    float v = (x[i] + b1[c] - mu) * rsqrtf(var + BN_EPS) * gamma[c] + beta[c];
    out[i] = v > 0.f ? v : 0.f;
}

// ---------------------------------------------------------------------------
extern "C" void kernel_launch(void* const* d_in, const int* in_sizes, int n_in,
                              void* d_out, int out_size, void* d_ws, size_t ws_size,
                              hipStream_t stream) {
    const float* x      = (const float*)d_in[0];
    const int*   ei     = (const int*)d_in[1];
    const float* W1     = (const float*)d_in[2];
    const float* a_src1 = (const float*)d_in[3];
    const float* a_dst1 = (const float*)d_in[4];
    const float* b1     = (const float*)d_in[5];
    const float* gamma1 = (const float*)d_in[6];
    const float* beta1  = (const float*)d_in[7];
    const float* Wm     = (const float*)d_in[8];
    const float* am_src = (const float*)d_in[9];
    const float* am_dst = (const float*)d_in[10];
    const float* bm     = (const float*)d_in[11];
    const float* Ws     = (const float*)d_in[12];
    const float* as_src = (const float*)d_in[13];
    const float* as_dst = (const float*)d_in[14];
    const float* bs     = (const float*)d_in[15];
    float* out = (float*)d_out;

    const long long N  = in_sizes[0] / 256;   // 50000
    const long long E  = in_sizes[1] / 2;     // 800000
    const long long ET = E + N;               // with self loops
    const int nb = (int)((N + 255) / 256);

    // ---- workspace layout (256B aligned bump allocator) ----
    size_t off = 0;
    auto alloc = [&](size_t bytes) -> char* {
        size_t o = off;
        off += (bytes + 255) & ~(size_t)255;
        return (char*)d_ws + o;
    };
    int*   flag    = (int*)  alloc(256);
    float* sums    = (float*)alloc(2 * HC * sizeof(float));
    int*   bsumv   = (int*)  alloc(256 * sizeof(int));
    unsigned short* T1h = (unsigned short*)alloc(65536 * 2);
    unsigned short* T1l = (unsigned short*)alloc(65536 * 2);
    unsigned short* Tmh = (unsigned short*)alloc(65536 * 2);
    unsigned short* Tml = (unsigned short*)alloc(65536 * 2);
    unsigned short* Tsh = (unsigned short*)alloc(65536 * 2);
    unsigned short* Tsl = (unsigned short*)alloc(65536 * 2);
    float* es      = (float*)alloc(N * NH * sizeof(float));
    float* ed      = (float*)alloc(N * NH * sizeof(float));
    int*   deg     = (int*)  alloc(N * sizeof(int));        // reused as cursor
    int*   rowptr  = (int*)  alloc((N + 1) * sizeof(int));
    int*   csr_src = (int*)  alloc(ET * sizeof(int));
    float* B1      = (float*)alloc(N * HC * sizeof(float)); // h1, then h
    float* B2      = (float*)alloc(N * HC * sizeof(float)); // agg1, then hm, then hs
    (void)ws_size; (void)n_in; (void)out_size;

    const int M = (int)N;
    dim3 ggrid((M + 127) / 128, 2);
    dim3 wgrid(8, 8, 3);
    const long long egrid = (ET + 255) / 256;
    const long long agrid = (N + 3) / 4;
    const long long ngrid = (N * HC + 255) / 256;

    detect_k<<<1, 256, 0, stream>>>(ei, E, flag);
    wconv_k<<<wgrid, 256, 0, stream>>>(W1, Wm, Ws, T1h, T1l, Tmh, Tml, Tsh, Tsl);

    // ---- CSR by destination ----
    hipMemsetAsync(deg, 0, N * sizeof(int), stream);
    hist_k<<<(int)egrid, 256, 0, stream>>>(ei, flag, E, ET, deg);
    scan1_k<<<nb, 256, 0, stream>>>(deg, rowptr, bsumv, N);
    scan2_k<<<1, 256, 0, stream>>>(bsumv, nb);
    scan3_k<<<nb + 1, 256, 0, stream>>>(rowptr, bsumv, N, ET);
    hipMemsetAsync(deg, 0, N * sizeof(int), stream);        // cursor
    scatter_k<<<(int)egrid, 256, 0, stream>>>(ei, flag, E, ET, rowptr, deg, csr_src);

    // ---- layer 1 (concat) ----
    gemm_mfma_k<<<ggrid, 256, 0, stream>>>(x, T1h, T1l, B1, M);
    scores_k<<<(int)N, 256, 0, stream>>>(B1, a_src1, a_dst1, N, es, ed);
    agg_concat_k<<<(int)agrid, 256, 0, stream>>>(rowptr, csr_src, es, ed, B1, N, B2);
    hipMemsetAsync(sums, 0, 2 * HC * sizeof(float), stream);
    bn_stats_k<<<nb, 256, 0, stream>>>(B2, b1, N, sums);
    bn_norm_relu_k<<<(int)ngrid, 256, 0, stream>>>(B2, b1, sums, gamma1, beta1, N, B1);

    // ---- layer 2, mean branch ----
    gemm_mfma_k<<<ggrid, 256, 0, stream>>>(B1, Tmh, Tml, B2, M);
    scores_k<<<(int)N, 256, 0, stream>>>(B2, am_src, am_dst, N, es, ed);
    agg_mean_k<<<(int)agrid, 256, 0, stream>>>(rowptr, csr_src, es, ed, B2, bm, N, out);

    // ---- layer 2, log_std branch ----
    gemm_mfma_k<<<ggrid, 256, 0, stream>>>(B1, Tsh, Tsl, B2, M);
    scores_k<<<(int)N, 256, 0, stream>>>(B2, as_src, as_dst, N, es, ed);
    agg_mean_k<<<(int)agrid, 256, 0, stream>>>(rowptr, csr_src, es, ed, B2, bs, N, out + N * 64);
}

// Round 5
// 802.169 us; speedup vs baseline: 13.7312x; 1.1445x over previous
//
#include <hip/hip_runtime.h>
#include <hip/hip_bf16.h>

// ---------------------------------------------------------------------------
// GAT encoder: 2x GATConv + BatchNorm/ReLU. N=50000, E=800000(+N self loops),
// Fin=256, H=4, C=64, L=64.
// Round 5: layer-2 hidden matrices stored bf16 (gather bytes halved; no BN
// downstream so rounding stays ~5e-4). Layer-1 stays fp32 (BN amplifies by
// ~1/sigma). Gather loops unrolled x2 for memory-level parallelism.
// GEMM: split-bf16 (hi+lo) 3-term MFMA, fp32 accumulate. CSR-by-dst gather
// aggregation, zero atomics in hot path.
// ---------------------------------------------------------------------------

#define HC 256   // H*C
#define NH 4     // heads
#define LRELU_SLOPE 0.2f
#define BN_EPS 1e-5f

typedef __attribute__((ext_vector_type(8))) short bf16x8_t;
typedef __attribute__((ext_vector_type(4))) float f32x4_t;
typedef __attribute__((ext_vector_type(4))) unsigned short u16x4_t;

__device__ __forceinline__ unsigned short f2bf(float f) {   // RNE
    unsigned u = __float_as_uint(f);
    u += 0x7fffu + ((u >> 16) & 1u);
    return (unsigned short)(u >> 16);
}
__device__ __forceinline__ float bf2f(unsigned short h) {
    return __uint_as_float(((unsigned)h) << 16);
}

// -------------------- edge-index dtype detection (int32 vs int64) ----------
__global__ void detect_k(const int* __restrict__ ei, long long E, int* __restrict__ flag) {
    __shared__ int any;
    if (threadIdx.x == 0) any = 0;
    __syncthreads();
    for (int i = threadIdx.x; i < 1024; i += blockDim.x) {
        long long idx = 2LL * i + 1;                 // hi-word position if int64
        if (idx < 2 * E && ei[idx] != 0) atomicOr(&any, 1);
    }
    __syncthreads();
    if (threadIdx.x == 0) flag[0] = (any == 0) ? 1 : 0;   // 1 => int64 layout
}

__device__ __forceinline__ void load_edge(const int* __restrict__ ei, int flag64,
                                          long long E, long long e, int& s, int& d) {
    if (e >= E) { s = d = (int)(e - E); return; }        // appended self-loops
    if (flag64) { s = ei[2 * e]; d = ei[2 * E + 2 * e]; }
    else        { s = ei[e];     d = ei[E + e]; }
}

// -------------------- CSR build: histogram -> scan -> scatter ---------------
__global__ __launch_bounds__(256) void hist_k(const int* __restrict__ ei,
                                              const int* __restrict__ flag,
                                              long long E, long long ET,
                                              int* __restrict__ deg) {
    long long e = blockIdx.x * 256LL + threadIdx.x;
    if (e >= ET) return;
    int s, d;
    load_edge(ei, flag[0], E, e, s, d);
    atomicAdd(&deg[d], 1);
}

__global__ __launch_bounds__(256) void scan1_k(const int* __restrict__ deg,
                                               int* __restrict__ excl,
                                               int* __restrict__ bsum, long long N) {
    __shared__ int buf[256];
    long long i = blockIdx.x * 256LL + threadIdx.x;
    int v = (i < N) ? deg[i] : 0;
    buf[threadIdx.x] = v;
    __syncthreads();
#pragma unroll
    for (int o = 1; o < 256; o <<= 1) {
        int t = (threadIdx.x >= o) ? buf[threadIdx.x - o] : 0;
        __syncthreads();
        buf[threadIdx.x] += t;
        __syncthreads();
    }
    if (i < N) excl[i] = buf[threadIdx.x] - v;
    if (threadIdx.x == 255) bsum[blockIdx.x] = buf[255];
}

__global__ __launch_bounds__(256) void scan2_k(int* __restrict__ bsum, int nb) {
    __shared__ int buf[256];
    int v = (threadIdx.x < nb) ? bsum[threadIdx.x] : 0;
    buf[threadIdx.x] = v;
    __syncthreads();
#pragma unroll
    for (int o = 1; o < 256; o <<= 1) {
        int t = (threadIdx.x >= o) ? buf[threadIdx.x - o] : 0;
        __syncthreads();
        buf[threadIdx.x] += t;
        __syncthreads();
    }
    if (threadIdx.x < nb) bsum[threadIdx.x] = buf[threadIdx.x] - v;
}

__global__ __launch_bounds__(256) void scan3_k(int* __restrict__ rowptr,
                                               const int* __restrict__ bsum,
                                               long long N, long long ET) {
    long long i = blockIdx.x * 256LL + threadIdx.x;
    if (i < N) rowptr[i] += bsum[blockIdx.x];
    if (i == N) rowptr[N] = (int)ET;
}

__global__ __launch_bounds__(256) void scatter_k(const int* __restrict__ ei,
                                                 const int* __restrict__ flag,
                                                 long long E, long long ET,
                                                 const int* __restrict__ rowptr,
                                                 int* __restrict__ cursor,
                                                 int* __restrict__ csr_src) {
    long long e = blockIdx.x * 256LL + threadIdx.x;
    if (e >= ET) return;
    int s, d;
    load_edge(ei, flag[0], E, e, s, d);
    int pos = rowptr[d] + atomicAdd(&cursor[d], 1);
    csr_src[pos] = s;
}

// -------------------- weight transpose + split-bf16 convert ----------------
__global__ __launch_bounds__(256) void wconv_k(const float* __restrict__ W1,
                                               const float* __restrict__ Wm,
                                               const float* __restrict__ Ws,
                                               unsigned short* __restrict__ T1h,
                                               unsigned short* __restrict__ T1l,
                                               unsigned short* __restrict__ Tmh,
                                               unsigned short* __restrict__ Tml,
                                               unsigned short* __restrict__ Tsh,
                                               unsigned short* __restrict__ Tsl) {
    __shared__ float tile[32][33];
    const float* W = blockIdx.z == 0 ? W1 : (blockIdx.z == 1 ? Wm : Ws);
    unsigned short* Th = blockIdx.z == 0 ? T1h : (blockIdx.z == 1 ? Tmh : Tsh);
    unsigned short* Tl = blockIdx.z == 0 ? T1l : (blockIdx.z == 1 ? Tml : Tsl);
    int k0 = blockIdx.y * 32, n0 = blockIdx.x * 32;
    int tx = threadIdx.x & 31, ty = threadIdx.x >> 5;
    for (int r = ty; r < 32; r += 8)
        tile[r][tx] = W[(k0 + r) * 256 + n0 + tx];
    __syncthreads();
    for (int r = ty; r < 32; r += 8) {
        float v = tile[tx][r];
        unsigned short h = f2bf(v);
        Th[(n0 + r) * 256 + k0 + tx] = h;
        Tl[(n0 + r) * 256 + k0 + tx] = f2bf(v - bf2f(h));
    }
}

// -------------------- split-bf16 MFMA GEMM ---------------------------------
// C[M,256] = A[M,256] @ W, W given as Bt[n][k] bf16 hi/lo.
// One wave -> 32 rows x 128 cols. No LDS, no barriers. OutT: float or ushort.
__device__ __forceinline__ void cvt_frag(const float* p, bf16x8_t& hi, bf16x8_t& lo) {
    const float4 x0 = *(const float4*)p;
    const float4 x1 = *(const float4*)(p + 4);
    float v[8] = {x0.x, x0.y, x0.z, x0.w, x1.x, x1.y, x1.z, x1.w};
#pragma unroll
    for (int i = 0; i < 8; ++i) {
        unsigned short h = f2bf(v[i]);
        hi[i] = (short)h;
        lo[i] = (short)f2bf(v[i] - bf2f(h));
    }
}

template <typename OutT>
__global__ __launch_bounds__(256) void gemm_mfma_k(const float* __restrict__ A,
                                                   const unsigned short* __restrict__ Bh,
                                                   const unsigned short* __restrict__ Bl,
                                                   OutT* __restrict__ C, int M) {
    const int warp = threadIdx.x >> 6;
    const int lane = threadIdx.x & 63;
    const int r0 = (blockIdx.x * 4 + warp) * 32;
    if (r0 >= M) return;
    const int nb = blockIdx.y * 128;
    const int q  = lane >> 4;       // k-group 0..3
    const int ln = lane & 15;
    int ra0 = r0 + ln;        if (ra0 >= M) ra0 = M - 1;
    int ra1 = r0 + 16 + ln;   if (ra1 >= M) ra1 = M - 1;
    const float* pa0 = A + (long long)ra0 * 256 + q * 8;
    const float* pa1 = A + (long long)ra1 * 256 + q * 8;
    const unsigned short* pbh = Bh + (long long)(nb + ln) * 256 + q * 8;
    const unsigned short* pbl = Bl + (long long)(nb + ln) * 256 + q * 8;

    f32x4_t acc0[8] = {}, acc1[8] = {};
#pragma unroll 2
    for (int ks = 0; ks < 8; ++ks) {           // K = 256 in steps of 32
        bf16x8_t a0h, a0l, a1h, a1l;
        cvt_frag(pa0, a0h, a0l);
        cvt_frag(pa1, a1h, a1l);
#pragma unroll
        for (int j = 0; j < 8; ++j) {          // col frags: n = nb + 16j + ln
            const bf16x8_t bh = *(const bf16x8_t*)(pbh + j * 4096);
            const bf16x8_t bl = *(const bf16x8_t*)(pbl + j * 4096);
            acc0[j] = __builtin_amdgcn_mfma_f32_16x16x32_bf16(a0h, bh, acc0[j], 0, 0, 0);
            acc0[j] = __builtin_amdgcn_mfma_f32_16x16x32_bf16(a0l, bh, acc0[j], 0, 0, 0);
            acc0[j] = __builtin_amdgcn_mfma_f32_16x16x32_bf16(a0h, bl, acc0[j], 0, 0, 0);
            acc1[j] = __builtin_amdgcn_mfma_f32_16x16x32_bf16(a1h, bh, acc1[j], 0, 0, 0);
            acc1[j] = __builtin_amdgcn_mfma_f32_16x16x32_bf16(a1l, bh, acc1[j], 0, 0, 0);
            acc1[j] = __builtin_amdgcn_mfma_f32_16x16x32_bf16(a1h, bl, acc1[j], 0, 0, 0);
        }
        pa0 += 32; pa1 += 32; pbh += 32; pbl += 32;
    }
#pragma unroll
    for (int j = 0; j < 8; ++j) {
        int col = nb + j * 16 + ln;
#pragma unroll
        for (int i = 0; i < 4; ++i) {
            int r = r0 + q * 4 + i;
            if (r < M) {
                float v = acc0[j][i];
                if constexpr (sizeof(OutT) == 2) C[(long long)r * 256 + col] = (OutT)f2bf(v);
                else                             C[(long long)r * 256 + col] = (OutT)v;
            }
            r += 16;
            if (r < M) {
                float v = acc1[j][i];
                if constexpr (sizeof(OutT) == 2) C[(long long)r * 256 + col] = (OutT)f2bf(v);
                else                             C[(long long)r * 256 + col] = (OutT)v;
            }
        }
    }
}

// -------------------- per-node attention scores (fp32 h) -------------------
__global__ __launch_bounds__(256) void scores_k(const float* __restrict__ hmat,
                                                const float* __restrict__ asrc,
                                                const float* __restrict__ adst,
                                                long long N,
                                                float* __restrict__ esrc,
                                                float* __restrict__ edst) {
    long long n = blockIdx.x;
    if (n >= N) return;
    int t = threadIdx.x;
    float v  = hmat[n * HC + t];
    float ps = v * asrc[t];
    float pd = v * adst[t];
#pragma unroll
    for (int k = 32; k >= 1; k >>= 1) {
        ps += __shfl_xor(ps, k);
        pd += __shfl_xor(pd, k);
    }
    if ((t & 63) == 0) {
        int head = t >> 6;
        esrc[n * NH + head] = ps;
        edst[n * NH + head] = pd;
    }
}

// -------------------- per-node attention scores (bf16 h) -------------------
__global__ __launch_bounds__(256) void scores_bf_k(const unsigned short* __restrict__ hmat,
                                                   const float* __restrict__ asrc,
                                                   const float* __restrict__ adst,
                                                   long long N,
                                                   float* __restrict__ esrc,
                                                   float* __restrict__ edst) {
    long long n = blockIdx.x;
    if (n >= N) return;
    int t = threadIdx.x;
    float v  = bf2f(hmat[n * HC + t]);
    float ps = v * asrc[t];
    float pd = v * adst[t];
#pragma unroll
    for (int k = 32; k >= 1; k >>= 1) {
        ps += __shfl_xor(ps, k);
        pd += __shfl_xor(pd, k);
    }
    if ((t & 63) == 0) {
        int head = t >> 6;
        esrc[n * NH + head] = ps;
        edst[n * NH + head] = pd;
    }
}

// -------------------- CSR gather aggregation, concat (layer 1, fp32) -------
// one wave per dst node; lane l owns cols [4l,4l+4), head = l>>4.
__global__ __launch_bounds__(256) void agg_concat_k(const int* __restrict__ rowptr,
                                                    const int* __restrict__ csr_src,
                                                    const float* __restrict__ esrc,
                                                    const float* __restrict__ edst,
                                                    const float* __restrict__ h,
                                                    long long N,
                                                    float* __restrict__ out) {
    long long d = blockIdx.x * 4LL + (threadIdx.x >> 6);
    if (d >= N) return;
    int lane = threadIdx.x & 63;
    int head = lane >> 4;
    float edv = edst[d * NH + head];
    int beg = rowptr[d], end = rowptr[d + 1];
    float a0 = 0.f, a1 = 0.f, a2 = 0.f, a3 = 0.f, den = 0.f;
    int i = beg;
    for (; i + 1 < end; i += 2) {               // 2 edges in flight
        int s0 = csr_src[i], s1 = csr_src[i + 1];
        float t0 = esrc[(long long)s0 * NH + head] + edv;
        float t1 = esrc[(long long)s1 * NH + head] + edv;
        float4 h0 = *(const float4*)&h[(long long)s0 * HC + lane * 4];
        float4 h1 = *(const float4*)&h[(long long)s1 * HC + lane * 4];
        t0 = t0 >= 0.f ? t0 : LRELU_SLOPE * t0;
        t1 = t1 >= 0.f ? t1 : LRELU_SLOPE * t1;
        float w0 = __expf(t0), w1 = __expf(t1);
        den += w0 + w1;
        a0 = fmaf(w0, h0.x, fmaf(w1, h1.x, a0));
        a1 = fmaf(w0, h0.y, fmaf(w1, h1.y, a1));
        a2 = fmaf(w0, h0.z, fmaf(w1, h1.z, a2));
        a3 = fmaf(w0, h0.w, fmaf(w1, h1.w, a3));
    }
    if (i < end) {
        int s = csr_src[i];
        float t = esrc[(long long)s * NH + head] + edv;
        t = t >= 0.f ? t : LRELU_SLOPE * t;
        float w = __expf(t);
        den += w;
        float4 hv = *(const float4*)&h[(long long)s * HC + lane * 4];
        a0 = fmaf(w, hv.x, a0); a1 = fmaf(w, hv.y, a1);
        a2 = fmaf(w, hv.z, a2); a3 = fmaf(w, hv.w, a3);
    }
    float inv = 1.0f / den;
    *(float4*)&out[d * HC + lane * 4] = make_float4(a0 * inv, a1 * inv, a2 * inv, a3 * inv);
}

// -------------------- CSR gather aggregation, head-mean (layer 2, bf16) ----
__global__ __launch_bounds__(256) void agg_mean_k(const int* __restrict__ rowptr,
                                                  const int* __restrict__ csr_src,
                                                  const float* __restrict__ esrc,
                                                  const float* __restrict__ edst,
                                                  const unsigned short* __restrict__ h,
                                                  const float* __restrict__ bias,
                                                  long long N,
                                                  float* __restrict__ outhalf) {
    long long d = blockIdx.x * 4LL + (threadIdx.x >> 6);
    if (d >= N) return;
    int lane = threadIdx.x & 63;
    int head = lane >> 4;
    float edv = edst[d * NH + head];
    int beg = rowptr[d], end = rowptr[d + 1];
    float a0 = 0.f, a1 = 0.f, a2 = 0.f, a3 = 0.f, den = 0.f;
    int i = beg;
    for (; i + 1 < end; i += 2) {               // 2 edges in flight
        int s0 = csr_src[i], s1 = csr_src[i + 1];
        float t0 = esrc[(long long)s0 * NH + head] + edv;
        float t1 = esrc[(long long)s1 * NH + head] + edv;
        u16x4_t h0 = *(const u16x4_t*)&h[(long long)s0 * HC + lane * 4];
        u16x4_t h1 = *(const u16x4_t*)&h[(long long)s1 * HC + lane * 4];
        t0 = t0 >= 0.f ? t0 : LRELU_SLOPE * t0;
        t1 = t1 >= 0.f ? t1 : LRELU_SLOPE * t1;
        float w0 = __expf(t0), w1 = __expf(t1);
        den += w0 + w1;
        a0 = fmaf(w0, bf2f(h0[0]), fmaf(w1, bf2f(h1[0]), a0));
        a1 = fmaf(w0, bf2f(h0[1]), fmaf(w1, bf2f(h1[1]), a1));
        a2 = fmaf(w0, bf2f(h0[2]), fmaf(w1, bf2f(h1[2]), a2));
        a3 = fmaf(w0, bf2f(h0[3]), fmaf(w1, bf2f(h1[3]), a3));
    }
    if (i < end) {
        int s = csr_src[i];
        float t = esrc[(long long)s * NH + head] + edv;
        t = t >= 0.f ? t : LRELU_SLOPE * t;
        float w = __expf(t);
        den += w;
        u16x4_t hv = *(const u16x4_t*)&h[(long long)s * HC + lane * 4];
        a0 = fmaf(w, bf2f(hv[0]), a0); a1 = fmaf(w, bf2f(hv[1]), a1);
        a2 = fmaf(w, bf2f(hv[2]), a2); a3 = fmaf(w, bf2f(hv[3]), a3);
    }
    float inv = 1.0f / den;
    a0 *= inv; a1 *= inv; a2 *= inv; a3 *= inv;
    a0 += __shfl_xor(a0, 16); a0 += __shfl_xor(a0, 32);
    a1 += __shfl_xor(a1, 16); a1 += __shfl_xor(a1, 32);
    a2 += __shfl_xor(a2, 16); a2 += __shfl_xor(a2, 32);
    a3 += __shfl_xor(a3, 16); a3 += __shfl_xor(a3, 32);
    if (lane < 16) {
        int cb = lane * 4;
        *(float4*)&outhalf[d * 64 + cb] =
            make_float4(0.25f * a0 + bias[cb],     0.25f * a1 + bias[cb + 1],
                        0.25f * a2 + bias[cb + 2], 0.25f * a3 + bias[cb + 3]);
    }
}

// -------------------- batchnorm ---------------------------------------------
__global__ __launch_bounds__(256) void bn_stats_k(const float* __restrict__ x,
                                                  const float* __restrict__ b1,
                                                  long long N, float* __restrict__ sums) {
    int c = threadIdx.x;
    long long r0 = (long long)blockIdx.x * 256;
    long long r1 = r0 + 256 < N ? r0 + 256 : N;
    float bias = b1[c];
    float s = 0.f, ss = 0.f;
    for (long long r = r0; r < r1; ++r) {
        float v = x[r * HC + c] + bias;
        s += v; ss += v * v;
    }
    atomicAdd(&sums[c], s);
    atomicAdd(&sums[HC + c], ss);
}

__global__ __launch_bounds__(256) void bn_norm_relu_k(const float* __restrict__ x,
                                                      const float* __restrict__ b1,
                                                      const float* __restrict__ sums,
                                                      const float* __restrict__ gamma,
                                                      const float* __restrict__ beta,
                                                      long long N, float* __restrict__ out) {
    long long i = blockIdx.x * 256LL + threadIdx.x;
    if (i >= N * HC) return;
    int c = (int)(i & (HC - 1));
    float invN = 1.0f / (float)N;
    float mu  = sums[c] * invN;
    float var = sums[HC + c] * invN - mu * mu;
    float v = (x[i] + b1[c] - mu) * rsqrtf(var + BN_EPS) * gamma[c] + beta[c];
    out[i] = v > 0.f ? v : 0.f;
}

// ---------------------------------------------------------------------------
extern "C" void kernel_launch(void* const* d_in, const int* in_sizes, int n_in,
                              void* d_out, int out_size, void* d_ws, size_t ws_size,
                              hipStream_t stream) {
    const float* x      = (const float*)d_in[0];
    const int*   ei     = (const int*)d_in[1];
    const float* W1     = (const float*)d_in[2];
    const float* a_src1 = (const float*)d_in[3];
    const float* a_dst1 = (const float*)d_in[4];
    const float* b1     = (const float*)d_in[5];
    const float* gamma1 = (const float*)d_in[6];
    const float* beta1  = (const float*)d_in[7];
    const float* Wm     = (const float*)d_in[8];
    const float* am_src = (const float*)d_in[9];
    const float* am_dst = (const float*)d_in[10];
    const float* bm     = (const float*)d_in[11];
    const float* Ws     = (const float*)d_in[12];
    const float* as_src = (const float*)d_in[13];
    const float* as_dst = (const float*)d_in[14];
    const float* bs     = (const float*)d_in[15];
    float* out = (float*)d_out;

    const long long N  = in_sizes[0] / 256;   // 50000
    const long long E  = in_sizes[1] / 2;     // 800000
    const long long ET = E + N;               // with self loops
    const int nb = (int)((N + 255) / 256);

    // ---- workspace layout (256B aligned bump allocator) ----
    size_t off = 0;
    auto alloc = [&](size_t bytes) -> char* {
        size_t o = off;
        off += (bytes + 255) & ~(size_t)255;
        return (char*)d_ws + o;
    };
    int*   flag    = (int*)  alloc(256);
    float* sums    = (float*)alloc(2 * HC * sizeof(float));
    int*   bsumv   = (int*)  alloc(256 * sizeof(int));
    unsigned short* T1h = (unsigned short*)alloc(65536 * 2);
    unsigned short* T1l = (unsigned short*)alloc(65536 * 2);
    unsigned short* Tmh = (unsigned short*)alloc(65536 * 2);
    unsigned short* Tml = (unsigned short*)alloc(65536 * 2);
    unsigned short* Tsh = (unsigned short*)alloc(65536 * 2);
    unsigned short* Tsl = (unsigned short*)alloc(65536 * 2);
    float* es      = (float*)alloc(N * NH * sizeof(float));
    float* ed      = (float*)alloc(N * NH * sizeof(float));
    int*   deg     = (int*)  alloc(N * sizeof(int));        // reused as cursor
    int*   rowptr  = (int*)  alloc((N + 1) * sizeof(int));
    int*   csr_src = (int*)  alloc(ET * sizeof(int));
    float* B1      = (float*)alloc(N * HC * sizeof(float)); // h1, then h
    float* B2      = (float*)alloc(N * HC * sizeof(float)); // agg1 fp32 / h2 bf16
    unsigned short* B2bf = (unsigned short*)B2;
    (void)ws_size; (void)n_in; (void)out_size;

    const int M = (int)N;
    dim3 ggrid((M + 127) / 128, 2);
    dim3 wgrid(8, 8, 3);
    const long long egrid = (ET + 255) / 256;
    const long long agrid = (N + 3) / 4;
    const long long ngrid = (N * HC + 255) / 256;

    detect_k<<<1, 256, 0, stream>>>(ei, E, flag);
    wconv_k<<<wgrid, 256, 0, stream>>>(W1, Wm, Ws, T1h, T1l, Tmh, Tml, Tsh, Tsl);

    // ---- CSR by destination ----
    hipMemsetAsync(deg, 0, N * sizeof(int), stream);
    hist_k<<<(int)egrid, 256, 0, stream>>>(ei, flag, E, ET, deg);
    scan1_k<<<nb, 256, 0, stream>>>(deg, rowptr, bsumv, N);
    scan2_k<<<1, 256, 0, stream>>>(bsumv, nb);
    scan3_k<<<nb + 1, 256, 0, stream>>>(rowptr, bsumv, N, ET);
    hipMemsetAsync(deg, 0, N * sizeof(int), stream);        // cursor
    scatter_k<<<(int)egrid, 256, 0, stream>>>(ei, flag, E, ET, rowptr, deg, csr_src);

    // ---- layer 1 (concat, fp32 throughout) ----
    gemm_mfma_k<float><<<ggrid, 256, 0, stream>>>(x, T1h, T1l, B1, M);
    scores_k<<<(int)N, 256, 0, stream>>>(B1, a_src1, a_dst1, N, es, ed);
    agg_concat_k<<<(int)agrid, 256, 0, stream>>>(rowptr, csr_src, es, ed, B1, N, B2);
    hipMemsetAsync(sums, 0, 2 * HC * sizeof(float), stream);
    bn_stats_k<<<nb, 256, 0, stream>>>(B2, b1, N, sums);
    bn_norm_relu_k<<<(int)ngrid, 256, 0, stream>>>(B2, b1, sums, gamma1, beta1, N, B1);

    // ---- layer 2, mean branch (h2 in bf16) ----
    gemm_mfma_k<unsigned short><<<ggrid, 256, 0, stream>>>(B1, Tmh, Tml, B2bf, M);
    scores_bf_k<<<(int)N, 256, 0, stream>>>(B2bf, am_src, am_dst, N, es, ed);
    agg_mean_k<<<(int)agrid, 256, 0, stream>>>(rowptr, csr_src, es, ed, B2bf, bm, N, out);

    // ---- layer 2, log_std branch (h2 in bf16) ----
    gemm_mfma_k<unsigned short><<<ggrid, 256, 0, stream>>>(B1, Tsh, Tsl, B2bf, M);
    scores_bf_k<<<(int)N, 256, 0, stream>>>(B2bf, as_src, as_dst, N, es, ed);
    agg_mean_k<<<(int)agrid, 256, 0, stream>>>(rowptr, csr_src, es, ed, B2bf, bs, N, out + N * 64);
}

// Round 6
// 616.708 us; speedup vs baseline: 17.8606x; 1.3007x over previous
//
#include <hip/hip_runtime.h>
#include <hip/hip_bf16.h>

// ---------------------------------------------------------------------------
// GAT encoder: 2x GATConv + BatchNorm/ReLU. N=50000, E=800000(+N self loops).
// Round 6:
//  - GEMM rebuilt: LDS-staged B (frag-major, double-buffered, reg-staged with
//    issue-early/write-late), A pre-split to bf16 hi/lo, attention scores
//    fused into the GEMM epilogue (head-aligned col-halves).
//  - layer-2 branches interleaved [N][hm256|hs256] bf16; both aggregations
//    fused into one CSR walk (1KB gather/edge serves mean & log_std).
// ---------------------------------------------------------------------------

#define HC 256   // H*C
#define NH 4     // heads
#define LRELU_SLOPE 0.2f
#define BN_EPS 1e-5f

typedef __attribute__((ext_vector_type(8))) short bf16x8_t;
typedef __attribute__((ext_vector_type(4))) float f32x4_t;
typedef __attribute__((ext_vector_type(8))) unsigned short u16x8_t;
typedef __attribute__((ext_vector_type(4))) unsigned short u16x4_t;
typedef unsigned short ushort_t;

__device__ __forceinline__ unsigned short f2bf(float f) {   // RNE
    unsigned u = __float_as_uint(f);
    u += 0x7fffu + ((u >> 16) & 1u);
    return (unsigned short)(u >> 16);
}
__device__ __forceinline__ float bf2f(unsigned short h) {
    return __uint_as_float(((unsigned)h) << 16);
}

// -------------------- edge-index dtype detection (int32 vs int64) ----------
__global__ void detect_k(const int* __restrict__ ei, long long E, int* __restrict__ flag) {
    __shared__ int any;
    if (threadIdx.x == 0) any = 0;
    __syncthreads();
    for (int i = threadIdx.x; i < 1024; i += blockDim.x) {
        long long idx = 2LL * i + 1;
        if (idx < 2 * E && ei[idx] != 0) atomicOr(&any, 1);
    }
    __syncthreads();
    if (threadIdx.x == 0) flag[0] = (any == 0) ? 1 : 0;   // 1 => int64 layout
}

__device__ __forceinline__ void load_edge(const int* __restrict__ ei, int flag64,
                                          long long E, long long e, int& s, int& d) {
    if (e >= E) { s = d = (int)(e - E); return; }        // appended self-loops
    if (flag64) { s = ei[2 * e]; d = ei[2 * E + 2 * e]; }
    else        { s = ei[e];     d = ei[E + e]; }
}

// -------------------- CSR build --------------------------------------------
__global__ __launch_bounds__(256) void hist_k(const int* __restrict__ ei,
                                              const int* __restrict__ flag,
                                              long long E, long long ET,
                                              int* __restrict__ deg) {
    long long e = blockIdx.x * 256LL + threadIdx.x;
    if (e >= ET) return;
    int s, d;
    load_edge(ei, flag[0], E, e, s, d);
    atomicAdd(&deg[d], 1);
}

__global__ __launch_bounds__(256) void scan1_k(const int* __restrict__ deg,
                                               int* __restrict__ excl,
                                               int* __restrict__ bsum, long long N) {
    __shared__ int buf[256];
    long long i = blockIdx.x * 256LL + threadIdx.x;
    int v = (i < N) ? deg[i] : 0;
    buf[threadIdx.x] = v;
    __syncthreads();
#pragma unroll
    for (int o = 1; o < 256; o <<= 1) {
        int t = (threadIdx.x >= o) ? buf[threadIdx.x - o] : 0;
        __syncthreads();
        buf[threadIdx.x] += t;
        __syncthreads();
    }
    if (i < N) excl[i] = buf[threadIdx.x] - v;
    if (threadIdx.x == 255) bsum[blockIdx.x] = buf[255];
}

__global__ __launch_bounds__(256) void scan2_k(int* __restrict__ bsum, int nb) {
    __shared__ int buf[256];
    int v = (threadIdx.x < nb) ? bsum[threadIdx.x] : 0;
    buf[threadIdx.x] = v;
    __syncthreads();
#pragma unroll
    for (int o = 1; o < 256; o <<= 1) {
        int t = (threadIdx.x >= o) ? buf[threadIdx.x - o] : 0;
        __syncthreads();
        buf[threadIdx.x] += t;
        __syncthreads();
    }
    if (threadIdx.x < nb) bsum[threadIdx.x] = buf[threadIdx.x] - v;
}

__global__ __launch_bounds__(256) void scan3_k(int* __restrict__ rowptr,
                                               const int* __restrict__ bsum,
                                               long long N, long long ET) {
    long long i = blockIdx.x * 256LL + threadIdx.x;
    if (i < N) rowptr[i] += bsum[blockIdx.x];
    if (i == N) rowptr[N] = (int)ET;
}

__global__ __launch_bounds__(256) void scatter_k(const int* __restrict__ ei,
                                                 const int* __restrict__ flag,
                                                 long long E, long long ET,
                                                 const int* __restrict__ rowptr,
                                                 int* __restrict__ cursor,
                                                 int* __restrict__ csr_src) {
    long long e = blockIdx.x * 256LL + threadIdx.x;
    if (e >= ET) return;
    int s, d;
    load_edge(ei, flag[0], E, e, s, d);
    int pos = rowptr[d] + atomicAdd(&cursor[d], 1);
    csr_src[pos] = s;
}

// -------------------- weight transpose + split-bf16 convert ----------------
__global__ __launch_bounds__(256) void wconv_k(const float* __restrict__ W1,
                                               const float* __restrict__ Wm,
                                               const float* __restrict__ Ws,
                                               ushort_t* __restrict__ T1h, ushort_t* __restrict__ T1l,
                                               ushort_t* __restrict__ Tmh, ushort_t* __restrict__ Tml,
                                               ushort_t* __restrict__ Tsh, ushort_t* __restrict__ Tsl) {
    __shared__ float tile[32][33];
    const float* W = blockIdx.z == 0 ? W1 : (blockIdx.z == 1 ? Wm : Ws);
    ushort_t* Th = blockIdx.z == 0 ? T1h : (blockIdx.z == 1 ? Tmh : Tsh);
    ushort_t* Tl = blockIdx.z == 0 ? T1l : (blockIdx.z == 1 ? Tml : Tsl);
    int k0 = blockIdx.y * 32, n0 = blockIdx.x * 32;
    int tx = threadIdx.x & 31, ty = threadIdx.x >> 5;
    for (int r = ty; r < 32; r += 8)
        tile[r][tx] = W[(k0 + r) * 256 + n0 + tx];
    __syncthreads();
    for (int r = ty; r < 32; r += 8) {
        float v = tile[tx][r];
        unsigned short h = f2bf(v);
        Th[(n0 + r) * 256 + k0 + tx] = h;
        Tl[(n0 + r) * 256 + k0 + tx] = f2bf(v - bf2f(h));
    }
}

// -------------------- fp32 -> bf16 hi/lo split (for x) ---------------------
__global__ __launch_bounds__(256) void split_k(const float* __restrict__ x,
                                               ushort_t* __restrict__ xh,
                                               ushort_t* __restrict__ xl, long long n4) {
    long long i = blockIdx.x * 256LL + threadIdx.x;
    if (i >= n4) return;
    float4 v = *(const float4*)&x[i * 4];
    u16x4_t h, l;
    float vv[4] = {v.x, v.y, v.z, v.w};
#pragma unroll
    for (int k = 0; k < 4; ++k) {
        unsigned short hh = f2bf(vv[k]);
        h[k] = hh;
        l[k] = f2bf(vv[k] - bf2f(hh));
    }
    *(u16x4_t*)&xh[i * 4] = h;
    *(u16x4_t*)&xl[i * 4] = l;
}

// -------------------- split-bf16 MFMA GEMM, LDS-staged B, fused scores -----
// C[M,256] = A @ W; A given split (Ah,Al) [M,256] bf16; B^T (Bh,Bl) [256,256].
// grid (ceil(M/128), 2): blockIdx.y = col-half (128 cols = heads 2y,2y+1).
// Epilogue writes C (fp32 or bf16, stride/offset params) and per-row
// e_src/e_dst for the 2 heads of this col-half.
template <typename OutT>
__global__ __launch_bounds__(256) void gemm_sb_k(const ushort_t* __restrict__ Ah,
                                                 const ushort_t* __restrict__ Al,
                                                 const ushort_t* __restrict__ Bh,
                                                 const ushort_t* __restrict__ Bl,
                                                 OutT* __restrict__ C, int cstride, int cofs,
                                                 const float* __restrict__ avs,
                                                 const float* __restrict__ avd,
                                                 float* __restrict__ es, float* __restrict__ ed,
                                                 int M) {
    __shared__ short Bs[2][8192];   // 2 x (8 j x 2 hl x 64 lanes x 8 bf16) = 32 KB
    const int tid  = threadIdx.x;
    const int warp = tid >> 6, lane = tid & 63;
    const int q = lane >> 4, ln = lane & 15;
    const int nb = blockIdx.y * 128;
    const int r0 = (blockIdx.x * 4 + warp) * 32;

    // staging descriptors: 4 slots per thread (1024 slots of 16B = 16 KB)
    const ushort_t* sg[4];
    int sdst[4];
#pragma unroll
    for (int it = 0; it < 4; ++it) {
        int idx = it * 256 + tid;
        int j = idx >> 7, hl = (idx >> 6) & 1, sl = idx & 63;
        const ushort_t* B0 = hl ? Bl : Bh;
        sg[it]   = B0 + (nb + j * 16 + (sl & 15)) * 256 + (sl >> 4) * 8;
        sdst[it] = idx * 8;
    }
    // A fragment pointers (clamped rows for the tail block)
    int ra0 = r0 + ln;      if (ra0 >= M) ra0 = M - 1;
    int ra1 = r0 + 16 + ln; if (ra1 >= M) ra1 = M - 1;
    const ushort_t* pa0h = Ah + (long long)ra0 * 256 + q * 8;
    const ushort_t* pa0l = Al + (long long)ra0 * 256 + q * 8;
    const ushort_t* pa1h = Ah + (long long)ra1 * 256 + q * 8;
    const ushort_t* pa1l = Al + (long long)ra1 * 256 + q * 8;

    f32x4_t acc0[8] = {}, acc1[8] = {};

    // prologue: stage ks=0 into buf 0
#pragma unroll
    for (int it = 0; it < 4; ++it)
        *(bf16x8_t*)&Bs[0][sdst[it]] = *(const bf16x8_t*)sg[it];
    __syncthreads();

    int buf = 0;
    for (int ks = 0; ks < 8; ++ks) {
        bf16x8_t stg[4];
        const bool more = (ks + 1 < 8);
        if (more) {
#pragma unroll
            for (int it = 0; it < 4; ++it)
                stg[it] = *(const bf16x8_t*)(sg[it] + (ks + 1) * 32);  // issue early
        }
        const int ko = ks * 32;
        bf16x8_t a0h = *(const bf16x8_t*)(pa0h + ko);
        bf16x8_t a0l = *(const bf16x8_t*)(pa0l + ko);
        bf16x8_t a1h = *(const bf16x8_t*)(pa1h + ko);
        bf16x8_t a1l = *(const bf16x8_t*)(pa1l + ko);
#pragma unroll
        for (int j = 0; j < 8; ++j) {
            bf16x8_t bh = *(const bf16x8_t*)&Bs[buf][(j * 2 + 0) * 512 + lane * 8];
            bf16x8_t bl = *(const bf16x8_t*)&Bs[buf][(j * 2 + 1) * 512 + lane * 8];
            acc0[j] = __builtin_amdgcn_mfma_f32_16x16x32_bf16(a0h, bh, acc0[j], 0, 0, 0);
            acc0[j] = __builtin_amdgcn_mfma_f32_16x16x32_bf16(a0l, bh, acc0[j], 0, 0, 0);
            acc0[j] = __builtin_amdgcn_mfma_f32_16x16x32_bf16(a0h, bl, acc0[j], 0, 0, 0);
            acc1[j] = __builtin_amdgcn_mfma_f32_16x16x32_bf16(a1h, bh, acc1[j], 0, 0, 0);
            acc1[j] = __builtin_amdgcn_mfma_f32_16x16x32_bf16(a1l, bh, acc1[j], 0, 0, 0);
            acc1[j] = __builtin_amdgcn_mfma_f32_16x16x32_bf16(a1h, bl, acc1[j], 0, 0, 0);
        }
        if (more) {
#pragma unroll
            for (int it = 0; it < 4; ++it)                               // write late
                *(bf16x8_t*)&Bs[buf ^ 1][sdst[it]] = stg[it];
        }
        __syncthreads();
        buf ^= 1;
    }

    // ---- epilogue 1: attention scores for heads {2y, 2y+1} ----
    float ps[2][4][2] = {}, pd[2][4][2] = {};
#pragma unroll
    for (int j = 0; j < 8; ++j) {
        int colv = nb + j * 16 + ln;
        float asv = avs[colv], adv = avd[colv];
        int hh = j >> 2;
#pragma unroll
        for (int i = 0; i < 4; ++i) {
            ps[0][i][hh] = fmaf(acc0[j][i], asv, ps[0][i][hh]);
            pd[0][i][hh] = fmaf(acc0[j][i], adv, pd[0][i][hh]);
            ps[1][i][hh] = fmaf(acc1[j][i], asv, ps[1][i][hh]);
            pd[1][i][hh] = fmaf(acc1[j][i], adv, pd[1][i][hh]);
        }
    }
#pragma unroll
    for (int m = 8; m >= 1; m >>= 1) {
#pragma unroll
        for (int rb = 0; rb < 2; ++rb)
#pragma unroll
            for (int i = 0; i < 4; ++i)
#pragma unroll
                for (int hh = 0; hh < 2; ++hh) {
                    ps[rb][i][hh] += __shfl_xor(ps[rb][i][hh], m);
                    pd[rb][i][hh] += __shfl_xor(pd[rb][i][hh], m);
                }
    }
    if (ln == 0) {
        int headbase = nb >> 6;
#pragma unroll
        for (int rb = 0; rb < 2; ++rb)
#pragma unroll
            for (int i = 0; i < 4; ++i) {
                int r = r0 + rb * 16 + q * 4 + i;
                if (r < M) {
                    es[r * NH + headbase]     = ps[rb][i][0];
                    es[r * NH + headbase + 1] = ps[rb][i][1];
                    ed[r * NH + headbase]     = pd[rb][i][0];
                    ed[r * NH + headbase + 1] = pd[rb][i][1];
                }
            }
    }

    // ---- epilogue 2: C write ----
#pragma unroll
    for (int j = 0; j < 8; ++j) {
        int col = nb + j * 16 + ln;
#pragma unroll
        for (int i = 0; i < 4; ++i) {
            int r = r0 + q * 4 + i;
            if (r < M) {
                float v = acc0[j][i];
                if constexpr (sizeof(OutT) == 2) C[(long long)r * cstride + cofs + col] = (OutT)f2bf(v);
                else                             C[(long long)r * cstride + cofs + col] = (OutT)v;
            }
            r += 16;
            if (r < M) {
                float v = acc1[j][i];
                if constexpr (sizeof(OutT) == 2) C[(long long)r * cstride + cofs + col] = (OutT)f2bf(v);
                else                             C[(long long)r * cstride + cofs + col] = (OutT)v;
            }
        }
    }
}

// -------------------- CSR gather aggregation, concat (layer 1, fp32) -------
__global__ __launch_bounds__(256) void agg_concat_k(const int* __restrict__ rowptr,
                                                    const int* __restrict__ csr_src,
                                                    const float* __restrict__ esrc,
                                                    const float* __restrict__ edst,
                                                    const float* __restrict__ h,
                                                    long long N,
                                                    float* __restrict__ out) {
    long long d = blockIdx.x * 4LL + (threadIdx.x >> 6);
    if (d >= N) return;
    int lane = threadIdx.x & 63;
    int head = lane >> 4;
    float edv = edst[d * NH + head];
    int beg = rowptr[d], end = rowptr[d + 1];
    float a0 = 0.f, a1 = 0.f, a2 = 0.f, a3 = 0.f, den = 0.f;
    int i = beg;
    for (; i + 1 < end; i += 2) {
        int s0 = csr_src[i], s1 = csr_src[i + 1];
        float t0 = esrc[(long long)s0 * NH + head] + edv;
        float t1 = esrc[(long long)s1 * NH + head] + edv;
        float4 h0 = *(const float4*)&h[(long long)s0 * HC + lane * 4];
        float4 h1 = *(const float4*)&h[(long long)s1 * HC + lane * 4];
        t0 = t0 >= 0.f ? t0 : LRELU_SLOPE * t0;
        t1 = t1 >= 0.f ? t1 : LRELU_SLOPE * t1;
        float w0 = __expf(t0), w1 = __expf(t1);
        den += w0 + w1;
        a0 = fmaf(w0, h0.x, fmaf(w1, h1.x, a0));
        a1 = fmaf(w0, h0.y, fmaf(w1, h1.y, a1));
        a2 = fmaf(w0, h0.z, fmaf(w1, h1.z, a2));
        a3 = fmaf(w0, h0.w, fmaf(w1, h1.w, a3));
    }
    if (i < end) {
        int s = csr_src[i];
        float t = esrc[(long long)s * NH + head] + edv;
        t = t >= 0.f ? t : LRELU_SLOPE * t;
        float w = __expf(t);
        den += w;
        float4 hv = *(const float4*)&h[(long long)s * HC + lane * 4];
        a0 = fmaf(w, hv.x, a0); a1 = fmaf(w, hv.y, a1);
        a2 = fmaf(w, hv.z, a2); a3 = fmaf(w, hv.w, a3);
    }
    float inv = 1.0f / den;
    *(float4*)&out[d * HC + lane * 4] = make_float4(a0 * inv, a1 * inv, a2 * inv, a3 * inv);
}

// -------------------- fused layer-2 aggregation (both branches) ------------
// h2 rows: [hm(256) | hs(256)] bf16, 1KB. lane l owns bf16 cols [8l, 8l+8):
// branch = l>>5, head = (l&31)>>3, within-head colgroup = l&7.
// Head-mean via shfl_xor 8,16; lanes with head==0 write 8 output cols.
__global__ __launch_bounds__(256) void agg_mean2_k(const int* __restrict__ rowptr,
                                                   const int* __restrict__ csr_src,
                                                   const float* __restrict__ esm,
                                                   const float* __restrict__ edm,
                                                   const float* __restrict__ ess,
                                                   const float* __restrict__ eds,
                                                   const ushort_t* __restrict__ h2,
                                                   const float* __restrict__ bm,
                                                   const float* __restrict__ bs,
                                                   long long N, float* __restrict__ out) {
    long long d = blockIdx.x * 4LL + (threadIdx.x >> 6);
    if (d >= N) return;
    int lane = threadIdx.x & 63;
    int br = lane >> 5, sub = lane & 31, head = sub >> 3;
    const float* esb = br ? ess : esm;
    const float* edb = br ? eds : edm;
    float edv = edb[d * NH + head];
    int beg = rowptr[d], end = rowptr[d + 1];
    float acc[8] = {};
    float den = 0.f;
    int i = beg;
    for (; i + 1 < end; i += 2) {
        int s0 = csr_src[i], s1 = csr_src[i + 1];
        float t0 = esb[(long long)s0 * NH + head] + edv;
        float t1 = esb[(long long)s1 * NH + head] + edv;
        u16x8_t v0 = *(const u16x8_t*)&h2[(long long)s0 * 512 + lane * 8];
        u16x8_t v1 = *(const u16x8_t*)&h2[(long long)s1 * 512 + lane * 8];
        t0 = t0 >= 0.f ? t0 : LRELU_SLOPE * t0;
        t1 = t1 >= 0.f ? t1 : LRELU_SLOPE * t1;
        float w0 = __expf(t0), w1 = __expf(t1);
        den += w0 + w1;
#pragma unroll
        for (int k = 0; k < 8; ++k)
            acc[k] = fmaf(w0, bf2f(v0[k]), fmaf(w1, bf2f(v1[k]), acc[k]));
    }
    if (i < end) {
        int s = csr_src[i];
        float t = esb[(long long)s * NH + head] + edv;
        t = t >= 0.f ? t : LRELU_SLOPE * t;
        float w = __expf(t);
        den += w;
        u16x8_t v = *(const u16x8_t*)&h2[(long long)s * 512 + lane * 8];
#pragma unroll
        for (int k = 0; k < 8; ++k)
            acc[k] = fmaf(w, bf2f(v[k]), acc[k]);
    }
    float inv = 1.0f / den;
#pragma unroll
    for (int k = 0; k < 8; ++k) {
        acc[k] *= inv;
        acc[k] += __shfl_xor(acc[k], 8);    // sum heads (bit3 of sub)
        acc[k] += __shfl_xor(acc[k], 16);   // (bit4 of sub)
    }
    if (head == 0) {   // sub < 8: this lane holds within-head cols sub*8 .. +8
        const float* bias = br ? bs : bm;
        float* ob = br ? out + N * 64 : out;
        int cb = sub * 8;
        float4 w0 = make_float4(0.25f * acc[0] + bias[cb],
                                0.25f * acc[1] + bias[cb + 1],
                                0.25f * acc[2] + bias[cb + 2],
                                0.25f * acc[3] + bias[cb + 3]);
        float4 w1 = make_float4(0.25f * acc[4] + bias[cb + 4],
                                0.25f * acc[5] + bias[cb + 5],
                                0.25f * acc[6] + bias[cb + 6],
                                0.25f * acc[7] + bias[cb + 7]);
        *(float4*)&ob[d * 64 + cb]     = w0;
        *(float4*)&ob[d * 64 + cb + 4] = w1;
    }
}

// -------------------- batchnorm ---------------------------------------------
__global__ __launch_bounds__(256) void bn_stats_k(const float* __restrict__ x,
                                                  const float* __restrict__ b1,
                                                  long long N, float* __restrict__ sums) {
    int c = threadIdx.x;
    long long r0 = (long long)blockIdx.x * 256;
    long long r1 = r0 + 256 < N ? r0 + 256 : N;
    float bias = b1[c];
    float s = 0.f, ss = 0.f;
    for (long long r = r0; r < r1; ++r) {
        float v = x[r * HC + c] + bias;
        s += v; ss += v * v;
    }
    atomicAdd(&sums[c], s);
    atomicAdd(&sums[HC + c], ss);
}

// BN + ReLU, writing h as split bf16 hi/lo (feeds layer-2 GEMM A directly)
__global__ __launch_bounds__(256) void bn_norm_relu_hl_k(const float* __restrict__ x,
                                                         const float* __restrict__ b1,
                                                         const float* __restrict__ sums,
                                                         const float* __restrict__ gamma,
                                                         const float* __restrict__ beta,
                                                         long long N,
                                                         ushort_t* __restrict__ hh,
                                                         ushort_t* __restrict__ hl) {
    long long i = blockIdx.x * 256LL + threadIdx.x;
    if (i >= N * HC) return;
    int c = (int)(i & (HC - 1));
    float invN = 1.0f / (float)N;
    float mu  = sums[c] * invN;
    float var = sums[HC + c] * invN - mu * mu;
    float v = (x[i] + b1[c] - mu) * rsqrtf(var + BN_EPS) * gamma[c] + beta[c];
    v = v > 0.f ? v : 0.f;
    unsigned short hi = f2bf(v);
    hh[i] = hi;
    hl[i] = f2bf(v - bf2f(hi));
}

// ---------------------------------------------------------------------------
extern "C" void kernel_launch(void* const* d_in, const int* in_sizes, int n_in,
                              void* d_out, int out_size, void* d_ws, size_t ws_size,
                              hipStream_t stream) {
    const float* x      = (const float*)d_in[0];
    const int*   ei     = (const int*)d_in[1];
    const float* W1     = (const float*)d_in[2];
    const float* a_src1 = (const float*)d_in[3];
    const float* a_dst1 = (const float*)d_in[4];
    const float* b1     = (const float*)d_in[5];
    const float* gamma1 = (const float*)d_in[6];
    const float* beta1  = (const float*)d_in[7];
    const float* Wm     = (const float*)d_in[8];
    const float* am_src = (const float*)d_in[9];
    const float* am_dst = (const float*)d_in[10];
    const float* bm     = (const float*)d_in[11];
    const float* Ws     = (const float*)d_in[12];
    const float* as_src = (const float*)d_in[13];
    const float* as_dst = (const float*)d_in[14];
    const float* bs     = (const float*)d_in[15];
    float* out = (float*)d_out;

    const long long N  = in_sizes[0] / 256;   // 50000
    const long long E  = in_sizes[1] / 2;     // 800000
    const long long ET = E + N;
    const int nb = (int)((N + 255) / 256);

    // ---- workspace layout (256B aligned), ~110MB ----
    size_t off = 0;
    auto alloc = [&](size_t bytes) -> char* {
        size_t o = off;
        off += (bytes + 255) & ~(size_t)255;
        return (char*)d_ws + o;
    };
    int*   flag    = (int*)  alloc(256);
    float* sums    = (float*)alloc(2 * HC * sizeof(float));
    int*   bsumv   = (int*)  alloc(256 * sizeof(int));
    ushort_t* T1h = (ushort_t*)alloc(65536 * 2);
    ushort_t* T1l = (ushort_t*)alloc(65536 * 2);
    ushort_t* Tmh = (ushort_t*)alloc(65536 * 2);
    ushort_t* Tml = (ushort_t*)alloc(65536 * 2);
    ushort_t* Tsh = (ushort_t*)alloc(65536 * 2);
    ushort_t* Tsl = (ushort_t*)alloc(65536 * 2);
    float* esm     = (float*)alloc(N * NH * sizeof(float));
    float* edm     = (float*)alloc(N * NH * sizeof(float));
    float* ess     = (float*)alloc(N * NH * sizeof(float));
    float* eds     = (float*)alloc(N * NH * sizeof(float));
    int*   deg     = (int*)  alloc(N * sizeof(int));        // reused as cursor
    int*   rowptr  = (int*)  alloc((N + 1) * sizeof(int));
    int*   csr_src = (int*)  alloc(ET * sizeof(int));
    float* B1      = (float*)alloc(N * HC * sizeof(float)); // h1 fp32 -> h hi|lo
    float* B2      = (float*)alloc(N * HC * sizeof(float)); // x hi|lo -> agg1 fp32 -> h2 [N,512] bf16
    (void)ws_size; (void)n_in; (void)out_size;

    ushort_t* xh = (ushort_t*)B2;            // x split lives in B2 until agg_concat
    ushort_t* xl = xh + N * 256;
    ushort_t* hh = (ushort_t*)B1;            // h split lives in B1 after BN
    ushort_t* hl = hh + N * 256;
    ushort_t* h2 = (ushort_t*)B2;            // layer-2 interleaved [N][512] bf16

    const int M = (int)N;
    dim3 ggrid((M + 127) / 128, 2);
    dim3 wgrid(8, 8, 3);
    const long long egrid = (ET + 255) / 256;
    const long long agrid = (N + 3) / 4;
    const long long ngrid = (N * HC + 255) / 256;
    const long long sgrid = (N * HC / 4 + 255) / 256;

    detect_k<<<1, 256, 0, stream>>>(ei, E, flag);
    wconv_k<<<wgrid, 256, 0, stream>>>(W1, Wm, Ws, T1h, T1l, Tmh, Tml, Tsh, Tsl);
    split_k<<<(int)sgrid, 256, 0, stream>>>(x, xh, xl, N * HC / 4);

    // ---- CSR by destination ----
    hipMemsetAsync(deg, 0, N * sizeof(int), stream);
    hist_k<<<(int)egrid, 256, 0, stream>>>(ei, flag, E, ET, deg);
    scan1_k<<<nb, 256, 0, stream>>>(deg, rowptr, bsumv, N);
    scan2_k<<<1, 256, 0, stream>>>(bsumv, nb);
    scan3_k<<<nb + 1, 256, 0, stream>>>(rowptr, bsumv, N, ET);
    hipMemsetAsync(deg, 0, N * sizeof(int), stream);
    scatter_k<<<(int)egrid, 256, 0, stream>>>(ei, flag, E, ET, rowptr, deg, csr_src);

    // ---- layer 1 (concat): GEMM (+scores) -> gather -> BN(+split) ----
    gemm_sb_k<float><<<ggrid, 256, 0, stream>>>(xh, xl, T1h, T1l,
                                                B1, HC, 0, a_src1, a_dst1, esm, edm, M);
    agg_concat_k<<<(int)agrid, 256, 0, stream>>>(rowptr, csr_src, esm, edm, B1, N, B2);
    hipMemsetAsync(sums, 0, 2 * HC * sizeof(float), stream);
    bn_stats_k<<<nb, 256, 0, stream>>>(B2, b1, N, sums);
    bn_norm_relu_hl_k<<<(int)ngrid, 256, 0, stream>>>(B2, b1, sums, gamma1, beta1, N, hh, hl);

    // ---- layer 2: two GEMMs (+scores) into interleaved h2, fused gather ----
    gemm_sb_k<ushort_t><<<ggrid, 256, 0, stream>>>(hh, hl, Tmh, Tml,
                                                   h2, 512, 0,   am_src, am_dst, esm, edm, M);
    gemm_sb_k<ushort_t><<<ggrid, 256, 0, stream>>>(hh, hl, Tsh, Tsl,
                                                   h2, 512, 256, as_src, as_dst, ess, eds, M);
    agg_mean2_k<<<(int)agrid, 256, 0, stream>>>(rowptr, csr_src, esm, edm, ess, eds,
                                                h2, bm, bs, N, out);
}

// Round 7
// 516.781 us; speedup vs baseline: 21.3142x; 1.1934x over previous
//
#include <hip/hip_runtime.h>
#include <hip/hip_bf16.h>

// ---------------------------------------------------------------------------
// GAT encoder: 2x GATConv + BatchNorm/ReLU. N=50000, E=800000(+N self loops).
// Round 7: full-bf16 datapath (error attenuated ~1/sqrt(deg) by aggregation
// before BN's amplification; empirically bf16-h2 moved absmax by 0).
//  - One plain-bf16 MFMA GEMM (256 cols/block, LDS dbuf B, fused 4-head
//    scores epilogue). Early-return stale-LDS bug fixed (clamp, don't exit).
//  - h1 gathered as bf16 (agg_concat fetch halved). BN emits bf16 h.
//  - CSR gather aggregation, zero atomics in hot path.
// ---------------------------------------------------------------------------

#define HC 256   // H*C
#define NH 4     // heads
#define LRELU_SLOPE 0.2f
#define BN_EPS 1e-5f

typedef __attribute__((ext_vector_type(8))) short bf16x8_t;
typedef __attribute__((ext_vector_type(4))) float f32x4_t;
typedef __attribute__((ext_vector_type(8))) unsigned short u16x8_t;
typedef __attribute__((ext_vector_type(4))) unsigned short u16x4_t;
typedef unsigned short ushort_t;

__device__ __forceinline__ unsigned short f2bf(float f) {   // RNE
    unsigned u = __float_as_uint(f);
    u += 0x7fffu + ((u >> 16) & 1u);
    return (unsigned short)(u >> 16);
}
__device__ __forceinline__ float bf2f(unsigned short h) {
    return __uint_as_float(((unsigned)h) << 16);
}

// -------------------- edge-index dtype detection (int32 vs int64) ----------
__global__ void detect_k(const int* __restrict__ ei, long long E, int* __restrict__ flag) {
    __shared__ int any;
    if (threadIdx.x == 0) any = 0;
    __syncthreads();
    for (int i = threadIdx.x; i < 1024; i += blockDim.x) {
        long long idx = 2LL * i + 1;
        if (idx < 2 * E && ei[idx] != 0) atomicOr(&any, 1);
    }
    __syncthreads();
    if (threadIdx.x == 0) flag[0] = (any == 0) ? 1 : 0;   // 1 => int64 layout
}

__device__ __forceinline__ void load_edge(const int* __restrict__ ei, int flag64,
                                          long long E, long long e, int& s, int& d) {
    if (e >= E) { s = d = (int)(e - E); return; }        // appended self-loops
    if (flag64) { s = ei[2 * e]; d = ei[2 * E + 2 * e]; }
    else        { s = ei[e];     d = ei[E + e]; }
}

// -------------------- CSR build --------------------------------------------
__global__ __launch_bounds__(256) void hist_k(const int* __restrict__ ei,
                                              const int* __restrict__ flag,
                                              long long E, long long ET,
                                              int* __restrict__ deg) {
    long long e = blockIdx.x * 256LL + threadIdx.x;
    if (e >= ET) return;
    int s, d;
    load_edge(ei, flag[0], E, e, s, d);
    atomicAdd(&deg[d], 1);
}

__global__ __launch_bounds__(256) void scan1_k(const int* __restrict__ deg,
                                               int* __restrict__ excl,
                                               int* __restrict__ bsum, long long N) {
    __shared__ int buf[256];
    long long i = blockIdx.x * 256LL + threadIdx.x;
    int v = (i < N) ? deg[i] : 0;
    buf[threadIdx.x] = v;
    __syncthreads();
#pragma unroll
    for (int o = 1; o < 256; o <<= 1) {
        int t = (threadIdx.x >= o) ? buf[threadIdx.x - o] : 0;
        __syncthreads();
        buf[threadIdx.x] += t;
        __syncthreads();
    }
    if (i < N) excl[i] = buf[threadIdx.x] - v;
    if (threadIdx.x == 255) bsum[blockIdx.x] = buf[255];
}

__global__ __launch_bounds__(256) void scan2_k(int* __restrict__ bsum, int nb) {
    __shared__ int buf[256];
    int v = (threadIdx.x < nb) ? bsum[threadIdx.x] : 0;
    buf[threadIdx.x] = v;
    __syncthreads();
#pragma unroll
    for (int o = 1; o < 256; o <<= 1) {
        int t = (threadIdx.x >= o) ? buf[threadIdx.x - o] : 0;
        __syncthreads();
        buf[threadIdx.x] += t;
        __syncthreads();
    }
    if (threadIdx.x < nb) bsum[threadIdx.x] = buf[threadIdx.x] - v;
}

__global__ __launch_bounds__(256) void scan3_k(int* __restrict__ rowptr,
                                               const int* __restrict__ bsum,
                                               long long N, long long ET) {
    long long i = blockIdx.x * 256LL + threadIdx.x;
    if (i < N) rowptr[i] += bsum[blockIdx.x];
    if (i == N) rowptr[N] = (int)ET;
}

__global__ __launch_bounds__(256) void scatter_k(const int* __restrict__ ei,
                                                 const int* __restrict__ flag,
                                                 long long E, long long ET,
                                                 const int* __restrict__ rowptr,
                                                 int* __restrict__ cursor,
                                                 int* __restrict__ csr_src) {
    long long e = blockIdx.x * 256LL + threadIdx.x;
    if (e >= ET) return;
    int s, d;
    load_edge(ei, flag[0], E, e, s, d);
    int pos = rowptr[d] + atomicAdd(&cursor[d], 1);
    csr_src[pos] = s;
}

// -------------------- weight transpose + bf16 convert ----------------------
__global__ __launch_bounds__(256) void wconv_k(const float* __restrict__ W1,
                                               const float* __restrict__ Wm,
                                               const float* __restrict__ Ws,
                                               ushort_t* __restrict__ T1,
                                               ushort_t* __restrict__ Tm,
                                               ushort_t* __restrict__ Ts) {
    __shared__ float tile[32][33];
    const float* W = blockIdx.z == 0 ? W1 : (blockIdx.z == 1 ? Wm : Ws);
    ushort_t* T = blockIdx.z == 0 ? T1 : (blockIdx.z == 1 ? Tm : Ts);
    int k0 = blockIdx.y * 32, n0 = blockIdx.x * 32;
    int tx = threadIdx.x & 31, ty = threadIdx.x >> 5;
    for (int r = ty; r < 32; r += 8)
        tile[r][tx] = W[(k0 + r) * 256 + n0 + tx];
    __syncthreads();
    for (int r = ty; r < 32; r += 8)
        T[(n0 + r) * 256 + k0 + tx] = f2bf(tile[tx][r]);
}

// -------------------- fp32 -> bf16 cast (for x) ----------------------------
__global__ __launch_bounds__(256) void cvt_k(const float* __restrict__ x,
                                             ushort_t* __restrict__ xh, long long n8) {
    long long i = blockIdx.x * 256LL + threadIdx.x;
    if (i >= n8) return;
    float4 v0 = *(const float4*)&x[i * 8];
    float4 v1 = *(const float4*)&x[i * 8 + 4];
    u16x8_t h;
    h[0] = f2bf(v0.x); h[1] = f2bf(v0.y); h[2] = f2bf(v0.z); h[3] = f2bf(v0.w);
    h[4] = f2bf(v1.x); h[5] = f2bf(v1.y); h[6] = f2bf(v1.z); h[7] = f2bf(v1.w);
    *(u16x8_t*)&xh[i * 8] = h;
}

// -------------------- bf16 MFMA GEMM, LDS-staged B, fused 4-head scores ----
// C[M,256](bf16, stride/ofs) = A[M,256](bf16) @ Bt^T; Bt[n][k] bf16.
// Block: 4 waves x 32 rows = 128 rows, all 256 cols. Epilogue: e_src/e_dst
// for all 4 heads + C write. NO early return (all warps must stage LDS).
__global__ __launch_bounds__(256) void gemm_bf_k(const ushort_t* __restrict__ A,
                                                 const ushort_t* __restrict__ Bt,
                                                 ushort_t* __restrict__ C, int cstride, int cofs,
                                                 const float* __restrict__ avs,
                                                 const float* __restrict__ avd,
                                                 float* __restrict__ es, float* __restrict__ ed,
                                                 int M) {
    __shared__ short Bs[2][8192];   // 2 x 16KB: 16 j x 64 lanes x 8 bf16
    const int tid  = threadIdx.x;
    const int warp = tid >> 6, lane = tid & 63;
    const int q = lane >> 4, ln = lane & 15;
    const int r0 = (blockIdx.x * 4 + warp) * 32;

    // staging: 4 slots/thread (1024 slots x 16B = 16KB per ks-step)
    const ushort_t* sg[4];
    int sdst[4];
#pragma unroll
    for (int it = 0; it < 4; ++it) {
        int idx = it * 256 + tid;
        int j = idx >> 6, sl = idx & 63;
        sg[it]   = Bt + (j * 16 + (sl & 15)) * 256 + (sl >> 4) * 8;
        sdst[it] = idx * 8;
    }
    int ra0 = r0 + ln;      if (ra0 >= M) ra0 = M - 1;
    int ra1 = r0 + 16 + ln; if (ra1 >= M) ra1 = M - 1;
    const ushort_t* pa0 = A + (long long)ra0 * 256 + q * 8;
    const ushort_t* pa1 = A + (long long)ra1 * 256 + q * 8;

    f32x4_t acc0[16] = {}, acc1[16] = {};
#pragma unroll
    for (int it = 0; it < 4; ++it)
        *(bf16x8_t*)&Bs[0][sdst[it]] = *(const bf16x8_t*)sg[it];
    __syncthreads();

    int buf = 0;
    for (int ks = 0; ks < 8; ++ks) {
        bf16x8_t stg[4];
        const bool more = (ks + 1 < 8);
        if (more) {
#pragma unroll
            for (int it = 0; it < 4; ++it)
                stg[it] = *(const bf16x8_t*)(sg[it] + (ks + 1) * 32);   // issue early
        }
        bf16x8_t a0 = *(const bf16x8_t*)(pa0 + ks * 32);
        bf16x8_t a1 = *(const bf16x8_t*)(pa1 + ks * 32);
#pragma unroll
        for (int j = 0; j < 16; ++j) {
            bf16x8_t b = *(const bf16x8_t*)&Bs[buf][(j * 64 + lane) * 8];
            acc0[j] = __builtin_amdgcn_mfma_f32_16x16x32_bf16(a0, b, acc0[j], 0, 0, 0);
            acc1[j] = __builtin_amdgcn_mfma_f32_16x16x32_bf16(a1, b, acc1[j], 0, 0, 0);
        }
        if (more) {
#pragma unroll
            for (int it = 0; it < 4; ++it)                              // write late
                *(bf16x8_t*)&Bs[buf ^ 1][sdst[it]] = stg[it];
        }
        __syncthreads();
        buf ^= 1;
    }

    // ---- epilogue 1: attention scores, head-pairs {0,1} then {2,3} ----
#pragma unroll
    for (int hp = 0; hp < 2; ++hp) {
        float ps[2][4][2] = {}, pd[2][4][2] = {};
#pragma unroll
        for (int jj = 0; jj < 8; ++jj) {
            int j = hp * 8 + jj;
            int colv = j * 16 + ln;
            float asv = avs[colv], adv = avd[colv];
            int hh = jj >> 2;
#pragma unroll
            for (int i = 0; i < 4; ++i) {
                ps[0][i][hh] = fmaf(acc0[j][i], asv, ps[0][i][hh]);
                pd[0][i][hh] = fmaf(acc0[j][i], adv, pd[0][i][hh]);
                ps[1][i][hh] = fmaf(acc1[j][i], asv, ps[1][i][hh]);
                pd[1][i][hh] = fmaf(acc1[j][i], adv, pd[1][i][hh]);
            }
        }
#pragma unroll
        for (int m = 8; m >= 1; m >>= 1)
#pragma unroll
            for (int rb = 0; rb < 2; ++rb)
#pragma unroll
                for (int i = 0; i < 4; ++i)
#pragma unroll
                    for (int hh = 0; hh < 2; ++hh) {
                        ps[rb][i][hh] += __shfl_xor(ps[rb][i][hh], m);
                        pd[rb][i][hh] += __shfl_xor(pd[rb][i][hh], m);
                    }
        if (ln == 0) {
#pragma unroll
            for (int rb = 0; rb < 2; ++rb)
#pragma unroll
                for (int i = 0; i < 4; ++i) {
                    int r = r0 + rb * 16 + q * 4 + i;
                    if (r < M) {
                        es[r * NH + hp * 2]     = ps[rb][i][0];
                        es[r * NH + hp * 2 + 1] = ps[rb][i][1];
                        ed[r * NH + hp * 2]     = pd[rb][i][0];
                        ed[r * NH + hp * 2 + 1] = pd[rb][i][1];
                    }
                }
        }
    }

    // ---- epilogue 2: C write (bf16) ----
#pragma unroll
    for (int j = 0; j < 16; ++j) {
        int col = j * 16 + ln;
#pragma unroll
        for (int i = 0; i < 4; ++i) {
            int r = r0 + q * 4 + i;
            if (r < M) C[(long long)r * cstride + cofs + col] = f2bf(acc0[j][i]);
            r += 16;
            if (r < M) C[(long long)r * cstride + cofs + col] = f2bf(acc1[j][i]);
        }
    }
}

// -------------------- CSR gather aggregation, concat (layer 1, bf16 h) -----
__global__ __launch_bounds__(256) void agg_concat_k(const int* __restrict__ rowptr,
                                                    const int* __restrict__ csr_src,
                                                    const float* __restrict__ esrc,
                                                    const float* __restrict__ edst,
                                                    const ushort_t* __restrict__ h,
                                                    long long N,
                                                    float* __restrict__ out) {
    long long d = blockIdx.x * 4LL + (threadIdx.x >> 6);
    if (d >= N) return;
    int lane = threadIdx.x & 63;
    int head = lane >> 4;
    float edv = edst[d * NH + head];
    int beg = rowptr[d], end = rowptr[d + 1];
    float a0 = 0.f, a1 = 0.f, a2 = 0.f, a3 = 0.f, den = 0.f;
    int i = beg;
    for (; i + 1 < end; i += 2) {
        int s0 = csr_src[i], s1 = csr_src[i + 1];
        float t0 = esrc[(long long)s0 * NH + head] + edv;
        float t1 = esrc[(long long)s1 * NH + head] + edv;
        u16x4_t h0 = *(const u16x4_t*)&h[(long long)s0 * HC + lane * 4];
        u16x4_t h1 = *(const u16x4_t*)&h[(long long)s1 * HC + lane * 4];
        t0 = t0 >= 0.f ? t0 : LRELU_SLOPE * t0;
        t1 = t1 >= 0.f ? t1 : LRELU_SLOPE * t1;
        float w0 = __expf(t0), w1 = __expf(t1);
        den += w0 + w1;
        a0 = fmaf(w0, bf2f(h0[0]), fmaf(w1, bf2f(h1[0]), a0));
        a1 = fmaf(w0, bf2f(h0[1]), fmaf(w1, bf2f(h1[1]), a1));
        a2 = fmaf(w0, bf2f(h0[2]), fmaf(w1, bf2f(h1[2]), a2));
        a3 = fmaf(w0, bf2f(h0[3]), fmaf(w1, bf2f(h1[3]), a3));
    }
    if (i < end) {
        int s = csr_src[i];
        float t = esrc[(long long)s * NH + head] + edv;
        t = t >= 0.f ? t : LRELU_SLOPE * t;
        float w = __expf(t);
        den += w;
        u16x4_t hv = *(const u16x4_t*)&h[(long long)s * HC + lane * 4];
        a0 = fmaf(w, bf2f(hv[0]), a0); a1 = fmaf(w, bf2f(hv[1]), a1);
        a2 = fmaf(w, bf2f(hv[2]), a2); a3 = fmaf(w, bf2f(hv[3]), a3);
    }
    float inv = 1.0f / den;
    *(float4*)&out[d * HC + lane * 4] = make_float4(a0 * inv, a1 * inv, a2 * inv, a3 * inv);
}

// -------------------- fused layer-2 aggregation (both branches, bf16) ------
__global__ __launch_bounds__(256) void agg_mean2_k(const int* __restrict__ rowptr,
                                                   const int* __restrict__ csr_src,
                                                   const float* __restrict__ esm,
                                                   const float* __restrict__ edm,
                                                   const float* __restrict__ ess,
                                                   const float* __restrict__ eds,
                                                   const ushort_t* __restrict__ h2,
                                                   const float* __restrict__ bm,
                                                   const float* __restrict__ bs,
                                                   long long N, float* __restrict__ out) {
    long long d = blockIdx.x * 4LL + (threadIdx.x >> 6);
    if (d >= N) return;
    int lane = threadIdx.x & 63;
    int br = lane >> 5, sub = lane & 31, head = sub >> 3;
    const float* esb = br ? ess : esm;
    const float* edb = br ? eds : edm;
    float edv = edb[d * NH + head];
    int beg = rowptr[d], end = rowptr[d + 1];
    float acc[8] = {};
    float den = 0.f;
    int i = beg;
    for (; i + 1 < end; i += 2) {
        int s0 = csr_src[i], s1 = csr_src[i + 1];
        float t0 = esb[(long long)s0 * NH + head] + edv;
        float t1 = esb[(long long)s1 * NH + head] + edv;
        u16x8_t v0 = *(const u16x8_t*)&h2[(long long)s0 * 512 + lane * 8];
        u16x8_t v1 = *(const u16x8_t*)&h2[(long long)s1 * 512 + lane * 8];
        t0 = t0 >= 0.f ? t0 : LRELU_SLOPE * t0;
        t1 = t1 >= 0.f ? t1 : LRELU_SLOPE * t1;
        float w0 = __expf(t0), w1 = __expf(t1);
        den += w0 + w1;
#pragma unroll
        for (int k = 0; k < 8; ++k)
            acc[k] = fmaf(w0, bf2f(v0[k]), fmaf(w1, bf2f(v1[k]), acc[k]));
    }
    if (i < end) {
        int s = csr_src[i];
        float t = esb[(long long)s * NH + head] + edv;
        t = t >= 0.f ? t : LRELU_SLOPE * t;
        float w = __expf(t);
        den += w;
        u16x8_t v = *(const u16x8_t*)&h2[(long long)s * 512 + lane * 8];
#pragma unroll
        for (int k = 0; k < 8; ++k)
            acc[k] = fmaf(w, bf2f(v[k]), acc[k]);
    }
    float inv = 1.0f / den;
#pragma unroll
    for (int k = 0; k < 8; ++k) {
        acc[k] *= inv;
        acc[k] += __shfl_xor(acc[k], 8);
        acc[k] += __shfl_xor(acc[k], 16);
    }
    if (head == 0) {
        const float* bias = br ? bs : bm;
        float* ob = br ? out + N * 64 : out;
        int cb = sub * 8;
        float4 w0 = make_float4(0.25f * acc[0] + bias[cb],
                                0.25f * acc[1] + bias[cb + 1],
                                0.25f * acc[2] + bias[cb + 2],
                                0.25f * acc[3] + bias[cb + 3]);
        float4 w1 = make_float4(0.25f * acc[4] + bias[cb + 4],
                                0.25f * acc[5] + bias[cb + 5],
                                0.25f * acc[6] + bias[cb + 6],
                                0.25f * acc[7] + bias[cb + 7]);
        *(float4*)&ob[d * 64 + cb]     = w0;
        *(float4*)&ob[d * 64 + cb + 4] = w1;
    }
}

// -------------------- batchnorm ---------------------------------------------
__global__ __launch_bounds__(256) void bn_stats_k(const float* __restrict__ x,
                                                  const float* __restrict__ b1,
                                                  long long N, float* __restrict__ sums) {
    int c = threadIdx.x;
    long long r0 = (long long)blockIdx.x * 256;
    long long r1 = r0 + 256 < N ? r0 + 256 : N;
    float bias = b1[c];
    float s = 0.f, ss = 0.f;
    for (long long r = r0; r < r1; ++r) {
        float v = x[r * HC + c] + bias;
        s += v; ss += v * v;
    }
    atomicAdd(&sums[c], s);
    atomicAdd(&sums[HC + c], ss);
}

// BN + ReLU -> bf16 h (feeds layer-2 GEMM A and nothing else)
__global__ __launch_bounds__(256) void bn_norm_relu_k(const float* __restrict__ x,
                                                      const float* __restrict__ b1,
                                                      const float* __restrict__ sums,
                                                      const float* __restrict__ gamma,
                                                      const float* __restrict__ beta,
                                                      long long N,
                                                      ushort_t* __restrict__ hh) {
    long long i = blockIdx.x * 256LL + threadIdx.x;
    if (i >= N * HC) return;
    int c = (int)(i & (HC - 1));
    float invN = 1.0f / (float)N;
    float mu  = sums[c] * invN;
    float var = sums[HC + c] * invN - mu * mu;
    float v = (x[i] + b1[c] - mu) * rsqrtf(var + BN_EPS) * gamma[c] + beta[c];
    v = v > 0.f ? v : 0.f;
    hh[i] = f2bf(v);
}

// ---------------------------------------------------------------------------
extern "C" void kernel_launch(void* const* d_in, const int* in_sizes, int n_in,
                              void* d_out, int out_size, void* d_ws, size_t ws_size,
                              hipStream_t stream) {
    const float* x      = (const float*)d_in[0];
    const int*   ei     = (const int*)d_in[1];
    const float* W1     = (const float*)d_in[2];
    const float* a_src1 = (const float*)d_in[3];
    const float* a_dst1 = (const float*)d_in[4];
    const float* b1     = (const float*)d_in[5];
    const float* gamma1 = (const float*)d_in[6];
    const float* beta1  = (const float*)d_in[7];
    const float* Wm     = (const float*)d_in[8];
    const float* am_src = (const float*)d_in[9];
    const float* am_dst = (const float*)d_in[10];
    const float* bm     = (const float*)d_in[11];
    const float* Ws     = (const float*)d_in[12];
    const float* as_src = (const float*)d_in[13];
    const float* as_dst = (const float*)d_in[14];
    const float* bs     = (const float*)d_in[15];
    float* out = (float*)d_out;

    const long long N  = in_sizes[0] / 256;   // 50000
    const long long E  = in_sizes[1] / 2;     // 800000
    const long long ET = E + N;
    const int nb = (int)((N + 255) / 256);

    // ---- workspace layout (256B aligned), ~85MB ----
    size_t off = 0;
    auto alloc = [&](size_t bytes) -> char* {
        size_t o = off;
        off += (bytes + 255) & ~(size_t)255;
        return (char*)d_ws + o;
    };
    int*   flag    = (int*)  alloc(256);
    float* sums    = (float*)alloc(2 * HC * sizeof(float));
    int*   bsumv   = (int*)  alloc(256 * sizeof(int));
    ushort_t* T1   = (ushort_t*)alloc(65536 * 2);
    ushort_t* Tm   = (ushort_t*)alloc(65536 * 2);
    ushort_t* Ts   = (ushort_t*)alloc(65536 * 2);
    float* esm     = (float*)alloc(N * NH * sizeof(float));
    float* edm     = (float*)alloc(N * NH * sizeof(float));
    float* ess     = (float*)alloc(N * NH * sizeof(float));
    float* eds     = (float*)alloc(N * NH * sizeof(float));
    int*   deg     = (int*)  alloc(N * sizeof(int));        // reused as cursor
    int*   rowptr  = (int*)  alloc((N + 1) * sizeof(int));
    int*   csr_src = (int*)  alloc(ET * sizeof(int));
    ushort_t* B1   = (ushort_t*)alloc(N * HC * 2);          // h1 bf16 -> h bf16
    char*     B2c  = alloc(N * 512 * 2);                    // xh -> agg1 fp32 -> h2 bf16
    (void)ws_size; (void)n_in; (void)out_size;

    ushort_t* xh   = (ushort_t*)B2c;      // [N,256] bf16
    float*    agg1 = (float*)B2c;         // [N,256] fp32
    ushort_t* h2   = (ushort_t*)B2c;      // [N,512] bf16 interleaved hm|hs

    const int M = (int)N;
    const int ggrid = (M + 127) / 128;
    dim3 wgrid(8, 8, 3);
    const long long egrid = (ET + 255) / 256;
    const long long agrid = (N + 3) / 4;
    const long long ngrid = (N * HC + 255) / 256;
    const long long cgrid = (N * HC / 8 + 255) / 256;

    detect_k<<<1, 256, 0, stream>>>(ei, E, flag);
    wconv_k<<<wgrid, 256, 0, stream>>>(W1, Wm, Ws, T1, Tm, Ts);
    cvt_k<<<(int)cgrid, 256, 0, stream>>>(x, xh, N * HC / 8);

    // ---- CSR by destination ----
    hipMemsetAsync(deg, 0, N * sizeof(int), stream);
    hist_k<<<(int)egrid, 256, 0, stream>>>(ei, flag, E, ET, deg);
    scan1_k<<<nb, 256, 0, stream>>>(deg, rowptr, bsumv, N);
    scan2_k<<<1, 256, 0, stream>>>(bsumv, nb);
    scan3_k<<<nb + 1, 256, 0, stream>>>(rowptr, bsumv, N, ET);
    hipMemsetAsync(deg, 0, N * sizeof(int), stream);
    scatter_k<<<(int)egrid, 256, 0, stream>>>(ei, flag, E, ET, rowptr, deg, csr_src);

    // ---- layer 1: GEMM(+scores) -> gather -> BN(->bf16 h) ----
    gemm_bf_k<<<ggrid, 256, 0, stream>>>(xh, T1, B1, HC, 0, a_src1, a_dst1, esm, edm, M);
    agg_concat_k<<<(int)agrid, 256, 0, stream>>>(rowptr, csr_src, esm, edm, B1, N, agg1);
    hipMemsetAsync(sums, 0, 2 * HC * sizeof(float), stream);
    bn_stats_k<<<nb, 256, 0, stream>>>(agg1, b1, N, sums);
    bn_norm_relu_k<<<(int)ngrid, 256, 0, stream>>>(agg1, b1, sums, gamma1, beta1, N, B1);

    // ---- layer 2: two GEMMs(+scores) into interleaved h2, fused gather ----
    gemm_bf_k<<<ggrid, 256, 0, stream>>>(B1, Tm, h2, 512, 0,   am_src, am_dst, esm, edm, M);
    gemm_bf_k<<<ggrid, 256, 0, stream>>>(B1, Ts, h2, 512, 256, as_src, as_dst, ess, eds, M);
    agg_mean2_k<<<(int)agrid, 256, 0, stream>>>(rowptr, csr_src, esm, edm, ess, eds,
                                                h2, bm, bs, N, out);
}

// Round 8
// 483.162 us; speedup vs baseline: 22.7972x; 1.0696x over previous
//
#include <hip/hip_runtime.h>
#include <hip/hip_bf16.h>

// ---------------------------------------------------------------------------
// GAT encoder: 2x GATConv + BatchNorm/ReLU. N=50000, E=800000(+N self loops).
// Round 8: dispatch diet (20 -> 13), cvt_k and bn_norm fused into the GEMMs
// (BN+ReLU applied on A-load via scale/shift), agg1 stored bf16, gather
// loops unrolled x4. Full-bf16 MFMA datapath, CSR gather aggregation.
// ---------------------------------------------------------------------------

#define HC 256   // H*C
#define NH 4     // heads
#define LRELU_SLOPE 0.2f
#define BN_EPS 1e-5f

typedef __attribute__((ext_vector_type(8))) short bf16x8_t;
typedef __attribute__((ext_vector_type(4))) float f32x4_t;
typedef __attribute__((ext_vector_type(8))) unsigned short u16x8_t;
typedef __attribute__((ext_vector_type(4))) unsigned short u16x4_t;
typedef unsigned short ushort_t;

__device__ __forceinline__ unsigned short f2bf(float f) {   // RNE
    unsigned u = __float_as_uint(f);
    u += 0x7fffu + ((u >> 16) & 1u);
    return (unsigned short)(u >> 16);
}
__device__ __forceinline__ float bf2f(unsigned short h) {
    return __uint_as_float(((unsigned)h) << 16);
}

// -------------------- init: zero deg+sums, detect int64 layout -------------
__global__ __launch_bounds__(256) void init_k(const int* __restrict__ ei, long long E,
                                              long long N, int* __restrict__ flag,
                                              int* __restrict__ deg, float* __restrict__ sums) {
    long long i = blockIdx.x * 256LL + threadIdx.x;
    if (i < N) deg[i] = 0;
    if (blockIdx.x == 0) {
        sums[threadIdx.x] = 0.f;
        sums[256 + threadIdx.x] = 0.f;
        __shared__ int any;
        if (threadIdx.x == 0) any = 0;
        __syncthreads();
        for (int t = threadIdx.x; t < 1024; t += 256) {
            long long idx = 2LL * t + 1;                 // hi word if int64
            if (idx < 2 * E && ei[idx] != 0) atomicOr(&any, 1);
        }
        __syncthreads();
        if (threadIdx.x == 0) flag[0] = (any == 0) ? 1 : 0;
    }
}

__device__ __forceinline__ void load_edge(const int* __restrict__ ei, int flag64,
                                          long long E, long long e, int& s, int& d) {
    if (e >= E) { s = d = (int)(e - E); return; }        // appended self-loops
    if (flag64) { s = ei[2 * e]; d = ei[2 * E + 2 * e]; }
    else        { s = ei[e];     d = ei[E + e]; }
}

// -------------------- CSR build --------------------------------------------
__global__ __launch_bounds__(256) void hist_k(const int* __restrict__ ei,
                                              const int* __restrict__ flag,
                                              long long E, long long ET,
                                              int* __restrict__ deg) {
    long long e = blockIdx.x * 256LL + threadIdx.x;
    if (e >= ET) return;
    int s, d;
    load_edge(ei, flag[0], E, e, s, d);
    atomicAdd(&deg[d], 1);
}

// per-block exclusive scan; zeroes deg afterwards (becomes scatter cursor)
__global__ __launch_bounds__(256) void scan1_k(int* __restrict__ deg,
                                               int* __restrict__ excl,
                                               int* __restrict__ bsum, long long N) {
    __shared__ int buf[256];
    long long i = blockIdx.x * 256LL + threadIdx.x;
    int v = (i < N) ? deg[i] : 0;
    buf[threadIdx.x] = v;
    __syncthreads();
#pragma unroll
    for (int o = 1; o < 256; o <<= 1) {
        int t = (threadIdx.x >= o) ? buf[threadIdx.x - o] : 0;
        __syncthreads();
        buf[threadIdx.x] += t;
        __syncthreads();
    }
    if (i < N) { excl[i] = buf[threadIdx.x] - v; deg[i] = 0; }
    if (threadIdx.x == 255) bsum[blockIdx.x] = buf[255];
}

__global__ __launch_bounds__(256) void scan2_k(int* __restrict__ bsum, int nb) {
    __shared__ int buf[256];
    int v = (threadIdx.x < nb) ? bsum[threadIdx.x] : 0;
    buf[threadIdx.x] = v;
    __syncthreads();
#pragma unroll
    for (int o = 1; o < 256; o <<= 1) {
        int t = (threadIdx.x >= o) ? buf[threadIdx.x - o] : 0;
        __syncthreads();
        buf[threadIdx.x] += t;
        __syncthreads();
    }
    if (threadIdx.x < nb) bsum[threadIdx.x] = buf[threadIdx.x] - v;
}

__global__ __launch_bounds__(256) void scan3_k(int* __restrict__ rowptr,
                                               const int* __restrict__ bsum,
                                               long long N, long long ET) {
    long long i = blockIdx.x * 256LL + threadIdx.x;
    if (i < N) rowptr[i] += bsum[blockIdx.x];
    if (i == N) rowptr[N] = (int)ET;
}

__global__ __launch_bounds__(256) void scatter_k(const int* __restrict__ ei,
                                                 const int* __restrict__ flag,
                                                 long long E, long long ET,
                                                 const int* __restrict__ rowptr,
                                                 int* __restrict__ cursor,
                                                 int* __restrict__ csr_src) {
    long long e = blockIdx.x * 256LL + threadIdx.x;
    if (e >= ET) return;
    int s, d;
    load_edge(ei, flag[0], E, e, s, d);
    int pos = rowptr[d] + atomicAdd(&cursor[d], 1);
    csr_src[pos] = s;
}

// -------------------- weight transpose + bf16 convert ----------------------
__global__ __launch_bounds__(256) void wconv_k(const float* __restrict__ W1,
                                               const float* __restrict__ Wm,
                                               const float* __restrict__ Ws,
                                               ushort_t* __restrict__ T1,
                                               ushort_t* __restrict__ Tm,
                                               ushort_t* __restrict__ Ts) {
    __shared__ float tile[32][33];
    const float* W = blockIdx.z == 0 ? W1 : (blockIdx.z == 1 ? Wm : Ws);
    ushort_t* T = blockIdx.z == 0 ? T1 : (blockIdx.z == 1 ? Tm : Ts);
    int k0 = blockIdx.y * 32, n0 = blockIdx.x * 32;
    int tx = threadIdx.x & 31, ty = threadIdx.x >> 5;
    for (int r = ty; r < 32; r += 8)
        tile[r][tx] = W[(k0 + r) * 256 + n0 + tx];
    __syncthreads();
    for (int r = ty; r < 32; r += 8)
        T[(n0 + r) * 256 + k0 + tx] = f2bf(tile[tx][r]);
}

// -------------------- bn finalize: scale/shift from sums -------------------
// stats were accumulated over (agg1 + b1); transform on A-load is
// a*scale[k] + shift[k] with shift = (b1-mu)*scale + beta.
__global__ __launch_bounds__(256) void bnfin_k(const float* __restrict__ sums,
                                               const float* __restrict__ b1,
                                               const float* __restrict__ gamma,
                                               const float* __restrict__ beta,
                                               long long N,
                                               float* __restrict__ scale,
                                               float* __restrict__ shift) {
    int c = threadIdx.x;
    float invN = 1.0f / (float)N;
    float mu  = sums[c] * invN;
    float var = sums[256 + c] * invN - mu * mu;
    float sc = gamma[c] * rsqrtf(var + BN_EPS);
    scale[c] = sc;
    shift[c] = (b1[c] - mu) * sc + beta[c];
}

// -------------------- A-fragment loaders -----------------------------------
__device__ __forceinline__ bf16x8_t ld_a_f32(const float* p) {
    float4 u0 = *(const float4*)p, u1 = *(const float4*)(p + 4);
    bf16x8_t r;
    r[0] = (short)f2bf(u0.x); r[1] = (short)f2bf(u0.y);
    r[2] = (short)f2bf(u0.z); r[3] = (short)f2bf(u0.w);
    r[4] = (short)f2bf(u1.x); r[5] = (short)f2bf(u1.y);
    r[6] = (short)f2bf(u1.z); r[7] = (short)f2bf(u1.w);
    return r;
}
__device__ __forceinline__ bf16x8_t ld_a_bn(const ushort_t* p,
                                            const float* __restrict__ scale,
                                            const float* __restrict__ shift, int k) {
    u16x8_t raw = *(const u16x8_t*)p;
    float4 sc0 = *(const float4*)&scale[k], sc1 = *(const float4*)&scale[k + 4];
    float4 sh0 = *(const float4*)&shift[k], sh1 = *(const float4*)&shift[k + 4];
    float sc[8] = {sc0.x, sc0.y, sc0.z, sc0.w, sc1.x, sc1.y, sc1.z, sc1.w};
    float sh[8] = {sh0.x, sh0.y, sh0.z, sh0.w, sh1.x, sh1.y, sh1.z, sh1.w};
    bf16x8_t r;
#pragma unroll
    for (int j = 0; j < 8; ++j) {
        float v = fmaf(bf2f(raw[j]), sc[j], sh[j]);
        v = v > 0.f ? v : 0.f;
        r[j] = (short)f2bf(v);
    }
    return r;
}

// -------------------- bf16 MFMA GEMM, LDS dbuf B, fused 4-head scores ------
// MODE 0: A = fp32 (x), plain.  MODE 1: A = bf16 agg1 with BN+ReLU on load.
// grid.z selects {Bt,av*,e*} set and C col-offset (z*256). No early return.
template <int MODE>
__global__ __launch_bounds__(256) void gemm_bf_k(const float* __restrict__ Af,
                                                 const ushort_t* __restrict__ Ab,
                                                 const ushort_t* __restrict__ Bt0,
                                                 const ushort_t* __restrict__ Bt1,
                                                 ushort_t* __restrict__ C, int cstride,
                                                 const float* __restrict__ scale,
                                                 const float* __restrict__ shift,
                                                 const float* __restrict__ avs0,
                                                 const float* __restrict__ avd0,
                                                 const float* __restrict__ avs1,
                                                 const float* __restrict__ avd1,
                                                 float* __restrict__ es0, float* __restrict__ ed0,
                                                 float* __restrict__ es1, float* __restrict__ ed1,
                                                 int M) {
    __shared__ short Bs[2][8192];   // 2 x 16KB
    const int z = blockIdx.z;
    const ushort_t* Bt = z ? Bt1 : Bt0;
    const float* avs = z ? avs1 : avs0;
    const float* avd = z ? avd1 : avd0;
    float* es = z ? es1 : es0;
    float* ed = z ? ed1 : ed0;
    const int cofs = z * 256;

    const int tid  = threadIdx.x;
    const int warp = tid >> 6, lane = tid & 63;
    const int q = lane >> 4, ln = lane & 15;
    const int r0 = (blockIdx.x * 4 + warp) * 32;

    const ushort_t* sg[4];
    int sdst[4];
#pragma unroll
    for (int it = 0; it < 4; ++it) {
        int idx = it * 256 + tid;
        int j = idx >> 6, sl = idx & 63;
        sg[it]   = Bt + (j * 16 + (sl & 15)) * 256 + (sl >> 4) * 8;
        sdst[it] = idx * 8;
    }
    int ra0 = r0 + ln;      if (ra0 >= M) ra0 = M - 1;
    int ra1 = r0 + 16 + ln; if (ra1 >= M) ra1 = M - 1;
    const float*    pa0f = Af ? Af + (long long)ra0 * 256 + q * 8 : nullptr;
    const float*    pa1f = Af ? Af + (long long)ra1 * 256 + q * 8 : nullptr;
    const ushort_t* pa0b = Ab ? Ab + (long long)ra0 * 256 + q * 8 : nullptr;
    const ushort_t* pa1b = Ab ? Ab + (long long)ra1 * 256 + q * 8 : nullptr;

    f32x4_t acc0[16] = {}, acc1[16] = {};
#pragma unroll
    for (int it = 0; it < 4; ++it)
        *(bf16x8_t*)&Bs[0][sdst[it]] = *(const bf16x8_t*)sg[it];
    __syncthreads();

    int buf = 0;
    for (int ks = 0; ks < 8; ++ks) {
        bf16x8_t stg[4];
        const bool more = (ks + 1 < 8);
        if (more) {
#pragma unroll
            for (int it = 0; it < 4; ++it)
                stg[it] = *(const bf16x8_t*)(sg[it] + (ks + 1) * 32);   // issue early
        }
        bf16x8_t a0, a1;
        if constexpr (MODE == 0) {
            a0 = ld_a_f32(pa0f + ks * 32);
            a1 = ld_a_f32(pa1f + ks * 32);
        } else {
            int k = q * 8 + ks * 32;
            a0 = ld_a_bn(pa0b + ks * 32, scale, shift, k);
            a1 = ld_a_bn(pa1b + ks * 32, scale, shift, k);
        }
#pragma unroll
        for (int j = 0; j < 16; ++j) {
            bf16x8_t b = *(const bf16x8_t*)&Bs[buf][(j * 64 + lane) * 8];
            acc0[j] = __builtin_amdgcn_mfma_f32_16x16x32_bf16(a0, b, acc0[j], 0, 0, 0);
            acc1[j] = __builtin_amdgcn_mfma_f32_16x16x32_bf16(a1, b, acc1[j], 0, 0, 0);
        }
        if (more) {
#pragma unroll
            for (int it = 0; it < 4; ++it)                              // write late
                *(bf16x8_t*)&Bs[buf ^ 1][sdst[it]] = stg[it];
        }
        __syncthreads();
        buf ^= 1;
    }

    // ---- epilogue 1: attention scores (4 heads via 2 head-pairs) ----
#pragma unroll
    for (int hp = 0; hp < 2; ++hp) {
        float ps[2][4][2] = {}, pd[2][4][2] = {};
#pragma unroll
        for (int jj = 0; jj < 8; ++jj) {
            int j = hp * 8 + jj;
            int colv = j * 16 + ln;
            float asv = avs[colv], adv = avd[colv];
            int hh = jj >> 2;
#pragma unroll
            for (int i = 0; i < 4; ++i) {
                ps[0][i][hh] = fmaf(acc0[j][i], asv, ps[0][i][hh]);
                pd[0][i][hh] = fmaf(acc0[j][i], adv, pd[0][i][hh]);
                ps[1][i][hh] = fmaf(acc1[j][i], asv, ps[1][i][hh]);
                pd[1][i][hh] = fmaf(acc1[j][i], adv, pd[1][i][hh]);
            }
        }
#pragma unroll
        for (int m = 8; m >= 1; m >>= 1)
#pragma unroll
            for (int rb = 0; rb < 2; ++rb)
#pragma unroll
                for (int i = 0; i < 4; ++i)
#pragma unroll
                    for (int hh = 0; hh < 2; ++hh) {
                        ps[rb][i][hh] += __shfl_xor(ps[rb][i][hh], m);
                        pd[rb][i][hh] += __shfl_xor(pd[rb][i][hh], m);
                    }
        if (ln == 0) {
#pragma unroll
            for (int rb = 0; rb < 2; ++rb)
#pragma unroll
                for (int i = 0; i < 4; ++i) {
                    int r = r0 + rb * 16 + q * 4 + i;
                    if (r < M) {
                        es[r * NH + hp * 2]     = ps[rb][i][0];
                        es[r * NH + hp * 2 + 1] = ps[rb][i][1];
                        ed[r * NH + hp * 2]     = pd[rb][i][0];
                        ed[r * NH + hp * 2 + 1] = pd[rb][i][1];
                    }
                }
        }
    }

    // ---- epilogue 2: C write (bf16) ----
#pragma unroll
    for (int j = 0; j < 16; ++j) {
        int col = cofs + j * 16 + ln;
#pragma unroll
        for (int i = 0; i < 4; ++i) {
            int r = r0 + q * 4 + i;
            if (r < M) C[(long long)r * cstride + col] = f2bf(acc0[j][i]);
            r += 16;
            if (r < M) C[(long long)r * cstride + col] = f2bf(acc1[j][i]);
        }
    }
}

// -------------------- CSR gather aggregation, concat (layer 1, bf16) -------
__global__ __launch_bounds__(256) void agg_concat_k(const int* __restrict__ rowptr,
                                                    const int* __restrict__ csr_src,
                                                    const float* __restrict__ esrc,
                                                    const float* __restrict__ edst,
                                                    const ushort_t* __restrict__ h,
                                                    long long N,
                                                    ushort_t* __restrict__ out) {
    long long d = blockIdx.x * 4LL + (threadIdx.x >> 6);
    if (d >= N) return;
    int lane = threadIdx.x & 63;
    int head = lane >> 4;
    float edv = edst[d * NH + head];
    int beg = rowptr[d], end = rowptr[d + 1];
    float a0 = 0.f, a1 = 0.f, a2 = 0.f, a3 = 0.f, den = 0.f;
    int i = beg;
    for (; i + 3 < end; i += 4) {
        int s0 = csr_src[i], s1 = csr_src[i + 1], s2 = csr_src[i + 2], s3 = csr_src[i + 3];
        float t0 = esrc[(long long)s0 * NH + head] + edv;
        float t1 = esrc[(long long)s1 * NH + head] + edv;
        float t2 = esrc[(long long)s2 * NH + head] + edv;
        float t3 = esrc[(long long)s3 * NH + head] + edv;
        u16x4_t h0 = *(const u16x4_t*)&h[(long long)s0 * HC + lane * 4];
        u16x4_t h1 = *(const u16x4_t*)&h[(long long)s1 * HC + lane * 4];
        u16x4_t h2 = *(const u16x4_t*)&h[(long long)s2 * HC + lane * 4];
        u16x4_t h3 = *(const u16x4_t*)&h[(long long)s3 * HC + lane * 4];
        t0 = t0 >= 0.f ? t0 : LRELU_SLOPE * t0;
        t1 = t1 >= 0.f ? t1 : LRELU_SLOPE * t1;
        t2 = t2 >= 0.f ? t2 : LRELU_SLOPE * t2;
        t3 = t3 >= 0.f ? t3 : LRELU_SLOPE * t3;
        float w0 = __expf(t0), w1 = __expf(t1), w2 = __expf(t2), w3 = __expf(t3);
        den += (w0 + w1) + (w2 + w3);
        a0 = fmaf(w0, bf2f(h0[0]), fmaf(w1, bf2f(h1[0]), fmaf(w2, bf2f(h2[0]), fmaf(w3, bf2f(h3[0]), a0))));
        a1 = fmaf(w0, bf2f(h0[1]), fmaf(w1, bf2f(h1[1]), fmaf(w2, bf2f(h2[1]), fmaf(w3, bf2f(h3[1]), a1))));
        a2 = fmaf(w0, bf2f(h0[2]), fmaf(w1, bf2f(h1[2]), fmaf(w2, bf2f(h2[2]), fmaf(w3, bf2f(h3[2]), a2))));
        a3 = fmaf(w0, bf2f(h0[3]), fmaf(w1, bf2f(h1[3]), fmaf(w2, bf2f(h2[3]), fmaf(w3, bf2f(h3[3]), a3))));
    }
    for (; i < end; ++i) {
        int s = csr_src[i];
        float t = esrc[(long long)s * NH + head] + edv;
        t = t >= 0.f ? t : LRELU_SLOPE * t;
        float w = __expf(t);
        den += w;
        u16x4_t hv = *(const u16x4_t*)&h[(long long)s * HC + lane * 4];
        a0 = fmaf(w, bf2f(hv[0]), a0); a1 = fmaf(w, bf2f(hv[1]), a1);
        a2 = fmaf(w, bf2f(hv[2]), a2); a3 = fmaf(w, bf2f(hv[3]), a3);
    }
    float inv = 1.0f / den;
    u16x4_t o;
    o[0] = f2bf(a0 * inv); o[1] = f2bf(a1 * inv);
    o[2] = f2bf(a2 * inv); o[3] = f2bf(a3 * inv);
    *(u16x4_t*)&out[d * HC + lane * 4] = o;
}

// -------------------- fused layer-2 aggregation (both branches) ------------
__global__ __launch_bounds__(256) void agg_mean2_k(const int* __restrict__ rowptr,
                                                   const int* __restrict__ csr_src,
                                                   const float* __restrict__ esm,
                                                   const float* __restrict__ edm,
                                                   const float* __restrict__ ess,
                                                   const float* __restrict__ eds,
                                                   const ushort_t* __restrict__ h2,
                                                   const float* __restrict__ bm,
                                                   const float* __restrict__ bs,
                                                   long long N, float* __restrict__ out) {
    long long d = blockIdx.x * 4LL + (threadIdx.x >> 6);
    if (d >= N) return;
    int lane = threadIdx.x & 63;
    int br = lane >> 5, sub = lane & 31, head = sub >> 3;
    const float* esb = br ? ess : esm;
    const float* edb = br ? eds : edm;
    float edv = edb[d * NH + head];
    int beg = rowptr[d], end = rowptr[d + 1];
    float acc[8] = {};
    float den = 0.f;
    int i = beg;
    for (; i + 3 < end; i += 4) {
        int s0 = csr_src[i], s1 = csr_src[i + 1], s2 = csr_src[i + 2], s3 = csr_src[i + 3];
        float t0 = esb[(long long)s0 * NH + head] + edv;
        float t1 = esb[(long long)s1 * NH + head] + edv;
        float t2 = esb[(long long)s2 * NH + head] + edv;
        float t3 = esb[(long long)s3 * NH + head] + edv;
        u16x8_t v0 = *(const u16x8_t*)&h2[(long long)s0 * 512 + lane * 8];
        u16x8_t v1 = *(const u16x8_t*)&h2[(long long)s1 * 512 + lane * 8];
        u16x8_t v2 = *(const u16x8_t*)&h2[(long long)s2 * 512 + lane * 8];
        u16x8_t v3 = *(const u16x8_t*)&h2[(long long)s3 * 512 + lane * 8];
        t0 = t0 >= 0.f ? t0 : LRELU_SLOPE * t0;
        t1 = t1 >= 0.f ? t1 : LRELU_SLOPE * t1;
        t2 = t2 >= 0.f ? t2 : LRELU_SLOPE * t2;
        t3 = t3 >= 0.f ? t3 : LRELU_SLOPE * t3;
        float w0 = __expf(t0), w1 = __expf(t1), w2 = __expf(t2), w3 = __expf(t3);
        den += (w0 + w1) + (w2 + w3);
#pragma unroll
        for (int k = 0; k < 8; ++k)
            acc[k] = fmaf(w0, bf2f(v0[k]),
                     fmaf(w1, bf2f(v1[k]),
                     fmaf(w2, bf2f(v2[k]),
                     fmaf(w3, bf2f(v3[k]), acc[k]))));
    }
    for (; i < end; ++i) {
        int s = csr_src[i];
        float t = esb[(long long)s * NH + head] + edv;
        t = t >= 0.f ? t : LRELU_SLOPE * t;
        float w = __expf(t);
        den += w;
        u16x8_t v = *(const u16x8_t*)&h2[(long long)s * 512 + lane * 8];
#pragma unroll
        for (int k = 0; k < 8; ++k)
            acc[k] = fmaf(w, bf2f(v[k]), acc[k]);
    }
    float inv = 1.0f / den;
#pragma unroll
    for (int k = 0; k < 8; ++k) {
        acc[k] *= inv;
        acc[k] += __shfl_xor(acc[k], 8);
        acc[k] += __shfl_xor(acc[k], 16);
    }
    if (head == 0) {
        const float* bias = br ? bs : bm;
        float* ob = br ? out + N * 64 : out;
        int cb = sub * 8;
        float4 w0 = make_float4(0.25f * acc[0] + bias[cb],
                                0.25f * acc[1] + bias[cb + 1],
                                0.25f * acc[2] + bias[cb + 2],
                                0.25f * acc[3] + bias[cb + 3]);
        float4 w1 = make_float4(0.25f * acc[4] + bias[cb + 4],
                                0.25f * acc[5] + bias[cb + 5],
                                0.25f * acc[6] + bias[cb + 6],
                                0.25f * acc[7] + bias[cb + 7]);
        *(float4*)&ob[d * 64 + cb]     = w0;
        *(float4*)&ob[d * 64 + cb + 4] = w1;
    }
}

// -------------------- batchnorm stats over (agg1 bf16 + b1) ----------------
__global__ __launch_bounds__(256) void bn_stats_k(const ushort_t* __restrict__ x,
                                                  const float* __restrict__ b1,
                                                  long long N, float* __restrict__ sums) {
    int c = threadIdx.x;
    long long r0 = (long long)blockIdx.x * 256;
    long long r1 = r0 + 256 < N ? r0 + 256 : N;
    float bias = b1[c];
    float s = 0.f, ss = 0.f;
    for (long long r = r0; r < r1; ++r) {
        float v = bf2f(x[r * HC + c]) + bias;
        s += v; ss += v * v;
    }
    atomicAdd(&sums[c], s);
    atomicAdd(&sums[HC + c], ss);
}

// ---------------------------------------------------------------------------
extern "C" void kernel_launch(void* const* d_in, const int* in_sizes, int n_in,
                              void* d_out, int out_size, void* d_ws, size_t ws_size,
                              hipStream_t stream) {
    const float* x      = (const float*)d_in[0];
    const int*   ei     = (const int*)d_in[1];
    const float* W1     = (const float*)d_in[2];
    const float* a_src1 = (const float*)d_in[3];
    const float* a_dst1 = (const float*)d_in[4];
    const float* b1     = (const float*)d_in[5];
    const float* gamma1 = (const float*)d_in[6];
    const float* beta1  = (const float*)d_in[7];
    const float* Wm     = (const float*)d_in[8];
    const float* am_src = (const float*)d_in[9];
    const float* am_dst = (const float*)d_in[10];
    const float* bm     = (const float*)d_in[11];
    const float* Ws     = (const float*)d_in[12];
    const float* as_src = (const float*)d_in[13];
    const float* as_dst = (const float*)d_in[14];
    const float* bs     = (const float*)d_in[15];
    float* out = (float*)d_out;

    const long long N  = in_sizes[0] / 256;   // 50000
    const long long E  = in_sizes[1] / 2;     // 800000
    const long long ET = E + N;
    const int nb = (int)((N + 255) / 256);

    // ---- workspace layout (256B aligned), ~112MB ----
    size_t off = 0;
    auto alloc = [&](size_t bytes) -> char* {
        size_t o = off;
        off += (bytes + 255) & ~(size_t)255;
        return (char*)d_ws + o;
    };
    int*   flag    = (int*)  alloc(256);
    float* sums    = (float*)alloc(2 * HC * sizeof(float));
    float* scale   = (float*)alloc(HC * sizeof(float));
    float* shift   = (float*)alloc(HC * sizeof(float));
    int*   bsumv   = (int*)  alloc(256 * sizeof(int));
    ushort_t* T1   = (ushort_t*)alloc(65536 * 2);
    ushort_t* Tm   = (ushort_t*)alloc(65536 * 2);
    ushort_t* Ts   = (ushort_t*)alloc(65536 * 2);
    float* esm     = (float*)alloc(N * NH * sizeof(float));
    float* edm     = (float*)alloc(N * NH * sizeof(float));
    float* ess     = (float*)alloc(N * NH * sizeof(float));
    float* eds     = (float*)alloc(N * NH * sizeof(float));
    int*   deg     = (int*)  alloc(N * sizeof(int));        // reused as cursor
    int*   rowptr  = (int*)  alloc((N + 1) * sizeof(int));
    int*   csr_src = (int*)  alloc(ET * sizeof(int));
    ushort_t* H1   = (ushort_t*)alloc(N * HC * 2);          // h1 bf16
    ushort_t* agg1 = (ushort_t*)alloc(N * HC * 2);          // agg1 bf16
    ushort_t* h2   = (ushort_t*)alloc(N * 512 * 2);         // [N,512] bf16 hm|hs
    (void)ws_size; (void)n_in; (void)out_size;

    const int M = (int)N;
    const int ggrid = (M + 127) / 128;
    dim3 wgrid(8, 8, 3);
    const long long egrid = (ET + 255) / 256;
    const long long agrid = (N + 3) / 4;

    init_k<<<nb, 256, 0, stream>>>(ei, E, N, flag, deg, sums);
    wconv_k<<<wgrid, 256, 0, stream>>>(W1, Wm, Ws, T1, Tm, Ts);

    // ---- CSR by destination ----
    hist_k<<<(int)egrid, 256, 0, stream>>>(ei, flag, E, ET, deg);
    scan1_k<<<nb, 256, 0, stream>>>(deg, rowptr, bsumv, N);     // also zeroes deg
    scan2_k<<<1, 256, 0, stream>>>(bsumv, nb);
    scan3_k<<<nb + 1, 256, 0, stream>>>(rowptr, bsumv, N, ET);
    scatter_k<<<(int)egrid, 256, 0, stream>>>(ei, flag, E, ET, rowptr, deg, csr_src);

    // ---- layer 1: GEMM(+scores) -> gather(bf16) -> stats -> scale/shift ----
    gemm_bf_k<0><<<dim3(ggrid, 1, 1), 256, 0, stream>>>(
        x, nullptr, T1, T1, H1, HC, nullptr, nullptr,
        a_src1, a_dst1, nullptr, nullptr, esm, edm, nullptr, nullptr, M);
    agg_concat_k<<<(int)agrid, 256, 0, stream>>>(rowptr, csr_src, esm, edm, H1, N, agg1);
    bn_stats_k<<<nb, 256, 0, stream>>>(agg1, b1, N, sums);
    bnfin_k<<<1, 256, 0, stream>>>(sums, b1, gamma1, beta1, N, scale, shift);

    // ---- layer 2: fused dual GEMM (BN on A-load, +scores) -> fused gather ----
    gemm_bf_k<1><<<dim3(ggrid, 1, 2), 256, 0, stream>>>(
        nullptr, agg1, Tm, Ts, h2, 512, scale, shift,
        am_src, am_dst, as_src, as_dst, esm, edm, ess, eds, M);
    agg_mean2_k<<<(int)agrid, 256, 0, stream>>>(rowptr, csr_src, esm, edm, ess, eds,
                                                h2, bm, bs, N, out);
}

// Round 10
// 480.123 us; speedup vs baseline: 22.9415x; 1.0063x over previous
//
#include <hip/hip_runtime.h>
#include <hip/hip_bf16.h>

// ---------------------------------------------------------------------------
// GAT encoder: 2x GATConv + BatchNorm/ReLU. N=50000, E=800000(+N self loops).
// Round 10: REVERT of the fp8-h2 experiment (absmax 0.0234 > 0.0196 budget).
// This is the round-8 configuration: full-bf16 MFMA datapath, CSR gather
// aggregation (zero hot-path atomics), BN fused into layer-2 GEMM A-load,
// attention scores fused into GEMM epilogues, h2 [N,512] bf16 interleaved.
// Gathers sit at the measured ~3.7 TB/s random-gather TCC wall; bf16 is the
// smallest dtype that passes the accuracy gate (fp8 measured: 0.0234 fail).
// ---------------------------------------------------------------------------

#define HC 256   // H*C
#define NH 4     // heads
#define LRELU_SLOPE 0.2f
#define BN_EPS 1e-5f

typedef __attribute__((ext_vector_type(8))) short bf16x8_t;
typedef __attribute__((ext_vector_type(4))) float f32x4_t;
typedef __attribute__((ext_vector_type(8))) unsigned short u16x8_t;
typedef __attribute__((ext_vector_type(4))) unsigned short u16x4_t;
typedef unsigned short ushort_t;

__device__ __forceinline__ unsigned short f2bf(float f) {   // RNE
    unsigned u = __float_as_uint(f);
    u += 0x7fffu + ((u >> 16) & 1u);
    return (unsigned short)(u >> 16);
}
__device__ __forceinline__ float bf2f(unsigned short h) {
    return __uint_as_float(((unsigned)h) << 16);
}

// -------------------- init: zero deg+sums, detect int64 layout -------------
__global__ __launch_bounds__(256) void init_k(const int* __restrict__ ei, long long E,
                                              long long N, int* __restrict__ flag,
                                              int* __restrict__ deg, float* __restrict__ sums) {
    long long i = blockIdx.x * 256LL + threadIdx.x;
    if (i < N) deg[i] = 0;
    if (blockIdx.x == 0) {
        sums[threadIdx.x] = 0.f;
        sums[256 + threadIdx.x] = 0.f;
        __shared__ int any;
        if (threadIdx.x == 0) any = 0;
        __syncthreads();
        for (int t = threadIdx.x; t < 1024; t += 256) {
            long long idx = 2LL * t + 1;                 // hi word if int64
            if (idx < 2 * E && ei[idx] != 0) atomicOr(&any, 1);
        }
        __syncthreads();
        if (threadIdx.x == 0) flag[0] = (any == 0) ? 1 : 0;
    }
}

__device__ __forceinline__ void load_edge(const int* __restrict__ ei, int flag64,
                                          long long E, long long e, int& s, int& d) {
    if (e >= E) { s = d = (int)(e - E); return; }        // appended self-loops
    if (flag64) { s = ei[2 * e]; d = ei[2 * E + 2 * e]; }
    else        { s = ei[e];     d = ei[E + e]; }
}

// -------------------- CSR build --------------------------------------------
__global__ __launch_bounds__(256) void hist_k(const int* __restrict__ ei,
                                              const int* __restrict__ flag,
                                              long long E, long long ET,
                                              int* __restrict__ deg) {
    long long e = blockIdx.x * 256LL + threadIdx.x;
    if (e >= ET) return;
    int s, d;
    load_edge(ei, flag[0], E, e, s, d);
    atomicAdd(&deg[d], 1);
}

// per-block exclusive scan; zeroes deg afterwards (becomes scatter cursor)
__global__ __launch_bounds__(256) void scan1_k(int* __restrict__ deg,
                                               int* __restrict__ excl,
                                               int* __restrict__ bsum, long long N) {
    __shared__ int buf[256];
    long long i = blockIdx.x * 256LL + threadIdx.x;
    int v = (i < N) ? deg[i] : 0;
    buf[threadIdx.x] = v;
    __syncthreads();
#pragma unroll
    for (int o = 1; o < 256; o <<= 1) {
        int t = (threadIdx.x >= o) ? buf[threadIdx.x - o] : 0;
        __syncthreads();
        buf[threadIdx.x] += t;
        __syncthreads();
    }
    if (i < N) { excl[i] = buf[threadIdx.x] - v; deg[i] = 0; }
    if (threadIdx.x == 255) bsum[blockIdx.x] = buf[255];
}

__global__ __launch_bounds__(256) void scan2_k(int* __restrict__ bsum, int nb) {
    __shared__ int buf[256];
    int v = (threadIdx.x < nb) ? bsum[threadIdx.x] : 0;
    buf[threadIdx.x] = v;
    __syncthreads();
#pragma unroll
    for (int o = 1; o < 256; o <<= 1) {
        int t = (threadIdx.x >= o) ? buf[threadIdx.x - o] : 0;
        __syncthreads();
        buf[threadIdx.x] += t;
        __syncthreads();
    }
    if (threadIdx.x < nb) bsum[threadIdx.x] = buf[threadIdx.x] - v;
}

__global__ __launch_bounds__(256) void scan3_k(int* __restrict__ rowptr,
                                               const int* __restrict__ bsum,
                                               long long N, long long ET) {
    long long i = blockIdx.x * 256LL + threadIdx.x;
    if (i < N) rowptr[i] += bsum[blockIdx.x];
    if (i == N) rowptr[N] = (int)ET;
}

__global__ __launch_bounds__(256) void scatter_k(const int* __restrict__ ei,
                                                 const int* __restrict__ flag,
                                                 long long E, long long ET,
                                                 const int* __restrict__ rowptr,
                                                 int* __restrict__ cursor,
                                                 int* __restrict__ csr_src) {
    long long e = blockIdx.x * 256LL + threadIdx.x;
    if (e >= ET) return;
    int s, d;
    load_edge(ei, flag[0], E, e, s, d);
    int pos = rowptr[d] + atomicAdd(&cursor[d], 1);
    csr_src[pos] = s;
}

// -------------------- weight transpose + bf16 convert ----------------------
__global__ __launch_bounds__(256) void wconv_k(const float* __restrict__ W1,
                                               const float* __restrict__ Wm,
                                               const float* __restrict__ Ws,
                                               ushort_t* __restrict__ T1,
                                               ushort_t* __restrict__ Tm,
                                               ushort_t* __restrict__ Ts) {
    __shared__ float tile[32][33];
    const float* W = blockIdx.z == 0 ? W1 : (blockIdx.z == 1 ? Wm : Ws);
    ushort_t* T = blockIdx.z == 0 ? T1 : (blockIdx.z == 1 ? Tm : Ts);
    int k0 = blockIdx.y * 32, n0 = blockIdx.x * 32;
    int tx = threadIdx.x & 31, ty = threadIdx.x >> 5;
    for (int r = ty; r < 32; r += 8)
        tile[r][tx] = W[(k0 + r) * 256 + n0 + tx];
    __syncthreads();
    for (int r = ty; r < 32; r += 8)
        T[(n0 + r) * 256 + k0 + tx] = f2bf(tile[tx][r]);
}

// -------------------- bn finalize: scale/shift from sums -------------------
// stats were accumulated over (agg1 + b1); transform on A-load is
// a*scale[k] + shift[k] with shift = (b1-mu)*scale + beta.
__global__ __launch_bounds__(256) void bnfin_k(const float* __restrict__ sums,
                                               const float* __restrict__ b1,
                                               const float* __restrict__ gamma,
                                               const float* __restrict__ beta,
                                               long long N,
                                               float* __restrict__ scale,
                                               float* __restrict__ shift) {
    int c = threadIdx.x;
    float invN = 1.0f / (float)N;
    float mu  = sums[c] * invN;
    float var = sums[256 + c] * invN - mu * mu;
    float sc = gamma[c] * rsqrtf(var + BN_EPS);
    scale[c] = sc;
    shift[c] = (b1[c] - mu) * sc + beta[c];
}

// -------------------- A-fragment loaders -----------------------------------
__device__ __forceinline__ bf16x8_t ld_a_f32(const float* p) {
    float4 u0 = *(const float4*)p, u1 = *(const float4*)(p + 4);
    bf16x8_t r;
    r[0] = (short)f2bf(u0.x); r[1] = (short)f2bf(u0.y);
    r[2] = (short)f2bf(u0.z); r[3] = (short)f2bf(u0.w);
    r[4] = (short)f2bf(u1.x); r[5] = (short)f2bf(u1.y);
    r[6] = (short)f2bf(u1.z); r[7] = (short)f2bf(u1.w);
    return r;
}
__device__ __forceinline__ bf16x8_t ld_a_bn(const ushort_t* p,
                                            const float* __restrict__ scale,
                                            const float* __restrict__ shift, int k) {
    u16x8_t raw = *(const u16x8_t*)p;
    float4 sc0 = *(const float4*)&scale[k], sc1 = *(const float4*)&scale[k + 4];
    float4 sh0 = *(const float4*)&shift[k], sh1 = *(const float4*)&shift[k + 4];
    float sc[8] = {sc0.x, sc0.y, sc0.z, sc0.w, sc1.x, sc1.y, sc1.z, sc1.w};
    float sh[8] = {sh0.x, sh0.y, sh0.z, sh0.w, sh1.x, sh1.y, sh1.z, sh1.w};
    bf16x8_t r;
#pragma unroll
    for (int j = 0; j < 8; ++j) {
        float v = fmaf(bf2f(raw[j]), sc[j], sh[j]);
        v = v > 0.f ? v : 0.f;
        r[j] = (short)f2bf(v);
    }
    return r;
}

// -------------------- bf16 MFMA GEMM, LDS dbuf B, fused 4-head scores ------
// MODE 0: A = fp32 (x), plain.  MODE 1: A = bf16 agg1 with BN+ReLU on load.
// grid.z selects {Bt,av*,e*} set and C col-offset (z*256). No early return.
template <int MODE>
__global__ __launch_bounds__(256) void gemm_bf_k(const float* __restrict__ Af,
                                                 const ushort_t* __restrict__ Ab,
                                                 const ushort_t* __restrict__ Bt0,
                                                 const ushort_t* __restrict__ Bt1,
                                                 ushort_t* __restrict__ C, int cstride,
                                                 const float* __restrict__ scale,
                                                 const float* __restrict__ shift,
                                                 const float* __restrict__ avs0,
                                                 const float* __restrict__ avd0,
                                                 const float* __restrict__ avs1,
                                                 const float* __restrict__ avd1,
                                                 float* __restrict__ es0, float* __restrict__ ed0,
                                                 float* __restrict__ es1, float* __restrict__ ed1,
                                                 int M) {
    __shared__ short Bs[2][8192];   // 2 x 16KB
    const int z = blockIdx.z;
    const ushort_t* Bt = z ? Bt1 : Bt0;
    const float* avs = z ? avs1 : avs0;
    const float* avd = z ? avd1 : avd0;
    float* es = z ? es1 : es0;
    float* ed = z ? ed1 : ed0;
    const int cofs = z * 256;

    const int tid  = threadIdx.x;
    const int warp = tid >> 6, lane = tid & 63;
    const int q = lane >> 4, ln = lane & 15;
    const int r0 = (blockIdx.x * 4 + warp) * 32;

    const ushort_t* sg[4];
    int sdst[4];
#pragma unroll
    for (int it = 0; it < 4; ++it) {
        int idx = it * 256 + tid;
        int j = idx >> 6, sl = idx & 63;
        sg[it]   = Bt + (j * 16 + (sl & 15)) * 256 + (sl >> 4) * 8;
        sdst[it] = idx * 8;
    }
    int ra0 = r0 + ln;      if (ra0 >= M) ra0 = M - 1;
    int ra1 = r0 + 16 + ln; if (ra1 >= M) ra1 = M - 1;
    const float*    pa0f = Af ? Af + (long long)ra0 * 256 + q * 8 : nullptr;
    const float*    pa1f = Af ? Af + (long long)ra1 * 256 + q * 8 : nullptr;
    const ushort_t* pa0b = Ab ? Ab + (long long)ra0 * 256 + q * 8 : nullptr;
    const ushort_t* pa1b = Ab ? Ab + (long long)ra1 * 256 + q * 8 : nullptr;

    f32x4_t acc0[16] = {}, acc1[16] = {};
#pragma unroll
    for (int it = 0; it < 4; ++it)
        *(bf16x8_t*)&Bs[0][sdst[it]] = *(const bf16x8_t*)sg[it];
    __syncthreads();

    int buf = 0;
    for (int ks = 0; ks < 8; ++ks) {
        bf16x8_t stg[4];
        const bool more = (ks + 1 < 8);
        if (more) {
#pragma unroll
            for (int it = 0; it < 4; ++it)
                stg[it] = *(const bf16x8_t*)(sg[it] + (ks + 1) * 32);   // issue early
        }
        bf16x8_t a0, a1;
        if constexpr (MODE == 0) {
            a0 = ld_a_f32(pa0f + ks * 32);
            a1 = ld_a_f32(pa1f + ks * 32);
        } else {
            int k = q * 8 + ks * 32;
            a0 = ld_a_bn(pa0b + ks * 32, scale, shift, k);
            a1 = ld_a_bn(pa1b + ks * 32, scale, shift, k);
        }
#pragma unroll
        for (int j = 0; j < 16; ++j) {
            bf16x8_t b = *(const bf16x8_t*)&Bs[buf][(j * 64 + lane) * 8];
            acc0[j] = __builtin_amdgcn_mfma_f32_16x16x32_bf16(a0, b, acc0[j], 0, 0, 0);
            acc1[j] = __builtin_amdgcn_mfma_f32_16x16x32_bf16(a1, b, acc1[j], 0, 0, 0);
        }
        if (more) {
#pragma unroll
            for (int it = 0; it < 4; ++it)                              // write late
                *(bf16x8_t*)&Bs[buf ^ 1][sdst[it]] = stg[it];
        }
        __syncthreads();
        buf ^= 1;
    }

    // ---- epilogue 1: attention scores (4 heads via 2 head-pairs) ----
#pragma unroll
    for (int hp = 0; hp < 2; ++hp) {
        float ps[2][4][2] = {}, pd[2][4][2] = {};
#pragma unroll
        for (int jj = 0; jj < 8; ++jj) {
            int j = hp * 8 + jj;
            int colv = j * 16 + ln;
            float asv = avs[colv], adv = avd[colv];
            int hh = jj >> 2;
#pragma unroll
            for (int i = 0; i < 4; ++i) {
                ps[0][i][hh] = fmaf(acc0[j][i], asv, ps[0][i][hh]);
                pd[0][i][hh] = fmaf(acc0[j][i], adv, pd[0][i][hh]);
                ps[1][i][hh] = fmaf(acc1[j][i], asv, ps[1][i][hh]);
                pd[1][i][hh] = fmaf(acc1[j][i], adv, pd[1][i][hh]);
            }
        }
#pragma unroll
        for (int m = 8; m >= 1; m >>= 1)
#pragma unroll
            for (int rb = 0; rb < 2; ++rb)
#pragma unroll
                for (int i = 0; i < 4; ++i)
#pragma unroll
                    for (int hh = 0; hh < 2; ++hh) {
                        ps[rb][i][hh] += __shfl_xor(ps[rb][i][hh], m);
                        pd[rb][i][hh] += __shfl_xor(pd[rb][i][hh], m);
                    }
        if (ln == 0) {
#pragma unroll
            for (int rb = 0; rb < 2; ++rb)
#pragma unroll
                for (int i = 0; i < 4; ++i) {
                    int r = r0 + rb * 16 + q * 4 + i;
                    if (r < M) {
                        es[r * NH + hp * 2]     = ps[rb][i][0];
                        es[r * NH + hp * 2 + 1] = ps[rb][i][1];
                        ed[r * NH + hp * 2]     = pd[rb][i][0];
                        ed[r * NH + hp * 2 + 1] = pd[rb][i][1];
                    }
                }
        }
    }

    // ---- epilogue 2: C write (bf16) ----
#pragma unroll
    for (int j = 0; j < 16; ++j) {
        int col = cofs + j * 16 + ln;
#pragma unroll
        for (int i = 0; i < 4; ++i) {
            int r = r0 + q * 4 + i;
            if (r < M) C[(long long)r * cstride + col] = f2bf(acc0[j][i]);
            r += 16;
            if (r < M) C[(long long)r * cstride + col] = f2bf(acc1[j][i]);
        }
    }
}

// -------------------- CSR gather aggregation, concat (layer 1, bf16) -------
__global__ __launch_bounds__(256) void agg_concat_k(const int* __restrict__ rowptr,
                                                    const int* __restrict__ csr_src,
                                                    const float* __restrict__ esrc,
                                                    const float* __restrict__ edst,
                                                    const ushort_t* __restrict__ h,
                                                    long long N,
                                                    ushort_t* __restrict__ out) {
    long long d = blockIdx.x * 4LL + (threadIdx.x >> 6);
    if (d >= N) return;
    int lane = threadIdx.x & 63;
    int head = lane >> 4;
    float edv = edst[d * NH + head];
    int beg = rowptr[d], end = rowptr[d + 1];
    float a0 = 0.f, a1 = 0.f, a2 = 0.f, a3 = 0.f, den = 0.f;
    int i = beg;
    for (; i + 3 < end; i += 4) {
        int s0 = csr_src[i], s1 = csr_src[i + 1], s2 = csr_src[i + 2], s3 = csr_src[i + 3];
        float t0 = esrc[(long long)s0 * NH + head] + edv;
        float t1 = esrc[(long long)s1 * NH + head] + edv;
        float t2 = esrc[(long long)s2 * NH + head] + edv;
        float t3 = esrc[(long long)s3 * NH + head] + edv;
        u16x4_t h0 = *(const u16x4_t*)&h[(long long)s0 * HC + lane * 4];
        u16x4_t h1 = *(const u16x4_t*)&h[(long long)s1 * HC + lane * 4];
        u16x4_t h2 = *(const u16x4_t*)&h[(long long)s2 * HC + lane * 4];
        u16x4_t h3 = *(const u16x4_t*)&h[(long long)s3 * HC + lane * 4];
        t0 = t0 >= 0.f ? t0 : LRELU_SLOPE * t0;
        t1 = t1 >= 0.f ? t1 : LRELU_SLOPE * t1;
        t2 = t2 >= 0.f ? t2 : LRELU_SLOPE * t2;
        t3 = t3 >= 0.f ? t3 : LRELU_SLOPE * t3;
        float w0 = __expf(t0), w1 = __expf(t1), w2 = __expf(t2), w3 = __expf(t3);
        den += (w0 + w1) + (w2 + w3);
        a0 = fmaf(w0, bf2f(h0[0]), fmaf(w1, bf2f(h1[0]), fmaf(w2, bf2f(h2[0]), fmaf(w3, bf2f(h3[0]), a0))));
        a1 = fmaf(w0, bf2f(h0[1]), fmaf(w1, bf2f(h1[1]), fmaf(w2, bf2f(h2[1]), fmaf(w3, bf2f(h3[1]), a1))));
        a2 = fmaf(w0, bf2f(h0[2]), fmaf(w1, bf2f(h1[2]), fmaf(w2, bf2f(h2[2]), fmaf(w3, bf2f(h3[2]), a2))));
        a3 = fmaf(w0, bf2f(h0[3]), fmaf(w1, bf2f(h1[3]), fmaf(w2, bf2f(h2[3]), fmaf(w3, bf2f(h3[3]), a3))));
    }
    for (; i < end; ++i) {
        int s = csr_src[i];
        float t = esrc[(long long)s * NH + head] + edv;
        t = t >= 0.f ? t : LRELU_SLOPE * t;
        float w = __expf(t);
        den += w;
        u16x4_t hv = *(const u16x4_t*)&h[(long long)s * HC + lane * 4];
        a0 = fmaf(w, bf2f(hv[0]), a0); a1 = fmaf(w, bf2f(hv[1]), a1);
        a2 = fmaf(w, bf2f(hv[2]), a2); a3 = fmaf(w, bf2f(hv[3]), a3);
    }
    float inv = 1.0f / den;
    u16x4_t o;
    o[0] = f2bf(a0 * inv); o[1] = f2bf(a1 * inv);
    o[2] = f2bf(a2 * inv); o[3] = f2bf(a3 * inv);
    *(u16x4_t*)&out[d * HC + lane * 4] = o;
}

// -------------------- fused layer-2 aggregation (both branches, bf16) ------
__global__ __launch_bounds__(256) void agg_mean2_k(const int* __restrict__ rowptr,
                                                   const int* __restrict__ csr_src,
                                                   const float* __restrict__ esm,
                                                   const float* __restrict__ edm,
                                                   const float* __restrict__ ess,
                                                   const float* __restrict__ eds,
                                                   const ushort_t* __restrict__ h2,
                                                   const float* __restrict__ bm,
                                                   const float* __restrict__ bs,
                                                   long long N, float* __restrict__ out) {
    long long d = blockIdx.x * 4LL + (threadIdx.x >> 6);
    if (d >= N) return;
    int lane = threadIdx.x & 63;
    int br = lane >> 5, sub = lane & 31, head = sub >> 3;
    const float* esb = br ? ess : esm;
    const float* edb = br ? eds : edm;
    float edv = edb[d * NH + head];
    int beg = rowptr[d], end = rowptr[d + 1];
    float acc[8] = {};
    float den = 0.f;
    int i = beg;
    for (; i + 3 < end; i += 4) {
        int s0 = csr_src[i], s1 = csr_src[i + 1], s2 = csr_src[i + 2], s3 = csr_src[i + 3];
        float t0 = esb[(long long)s0 * NH + head] + edv;
        float t1 = esb[(long long)s1 * NH + head] + edv;
        float t2 = esb[(long long)s2 * NH + head] + edv;
        float t3 = esb[(long long)s3 * NH + head] + edv;
        u16x8_t v0 = *(const u16x8_t*)&h2[(long long)s0 * 512 + lane * 8];
        u16x8_t v1 = *(const u16x8_t*)&h2[(long long)s1 * 512 + lane * 8];
        u16x8_t v2 = *(const u16x8_t*)&h2[(long long)s2 * 512 + lane * 8];
        u16x8_t v3 = *(const u16x8_t*)&h2[(long long)s3 * 512 + lane * 8];
        t0 = t0 >= 0.f ? t0 : LRELU_SLOPE * t0;
        t1 = t1 >= 0.f ? t1 : LRELU_SLOPE * t1;
        t2 = t2 >= 0.f ? t2 : LRELU_SLOPE * t2;
        t3 = t3 >= 0.f ? t3 : LRELU_SLOPE * t3;
        float w0 = __expf(t0), w1 = __expf(t1), w2 = __expf(t2), w3 = __expf(t3);
        den += (w0 + w1) + (w2 + w3);
#pragma unroll
        for (int k = 0; k < 8; ++k)
            acc[k] = fmaf(w0, bf2f(v0[k]),
                     fmaf(w1, bf2f(v1[k]),
                     fmaf(w2, bf2f(v2[k]),
                     fmaf(w3, bf2f(v3[k]), acc[k]))));
    }
    for (; i < end; ++i) {
        int s = csr_src[i];
        float t = esb[(long long)s * NH + head] + edv;
        t = t >= 0.f ? t : LRELU_SLOPE * t;
        float w = __expf(t);
        den += w;
        u16x8_t v = *(const u16x8_t*)&h2[(long long)s * 512 + lane * 8];
#pragma unroll
        for (int k = 0; k < 8; ++k)
            acc[k] = fmaf(w, bf2f(v[k]), acc[k]);
    }
    float inv = 1.0f / den;
#pragma unroll
    for (int k = 0; k < 8; ++k) {
        acc[k] *= inv;
        acc[k] += __shfl_xor(acc[k], 8);
        acc[k] += __shfl_xor(acc[k], 16);
    }
    if (head == 0) {
        const float* bias = br ? bs : bm;
        float* ob = br ? out + N * 64 : out;
        int cb = sub * 8;
        float4 w0 = make_float4(0.25f * acc[0] + bias[cb],
                                0.25f * acc[1] + bias[cb + 1],
                                0.25f * acc[2] + bias[cb + 2],
                                0.25f * acc[3] + bias[cb + 3]);
        float4 w1 = make_float4(0.25f * acc[4] + bias[cb + 4],
                                0.25f * acc[5] + bias[cb + 5],
                                0.25f * acc[6] + bias[cb + 6],
                                0.25f * acc[7] + bias[cb + 7]);
        *(float4*)&ob[d * 64 + cb]     = w0;
        *(float4*)&ob[d * 64 + cb + 4] = w1;
    }
}

// -------------------- batchnorm stats over (agg1 bf16 + b1) ----------------
__global__ __launch_bounds__(256) void bn_stats_k(const ushort_t* __restrict__ x,
                                                  const float* __restrict__ b1,
                                                  long long N, float* __restrict__ sums) {
    int c = threadIdx.x;
    long long r0 = (long long)blockIdx.x * 256;
    long long r1 = r0 + 256 < N ? r0 + 256 : N;
    float bias = b1[c];
    float s = 0.f, ss = 0.f;
    for (long long r = r0; r < r1; ++r) {
        float v = bf2f(x[r * HC + c]) + bias;
        s += v; ss += v * v;
    }
    atomicAdd(&sums[c], s);
    atomicAdd(&sums[HC + c], ss);
}

// ---------------------------------------------------------------------------
extern "C" void kernel_launch(void* const* d_in, const int* in_sizes, int n_in,
                              void* d_out, int out_size, void* d_ws, size_t ws_size,
                              hipStream_t stream) {
    const float* x      = (const float*)d_in[0];
    const int*   ei     = (const int*)d_in[1];
    const float* W1     = (const float*)d_in[2];
    const float* a_src1 = (const float*)d_in[3];
    const float* a_dst1 = (const float*)d_in[4];
    const float* b1     = (const float*)d_in[5];
    const float* gamma1 = (const float*)d_in[6];
    const float* beta1  = (const float*)d_in[7];
    const float* Wm     = (const float*)d_in[8];
    const float* am_src = (const float*)d_in[9];
    const float* am_dst = (const float*)d_in[10];
    const float* bm     = (const float*)d_in[11];
    const float* Ws     = (const float*)d_in[12];
    const float* as_src = (const float*)d_in[13];
    const float* as_dst = (const float*)d_in[14];
    const float* bs     = (const float*)d_in[15];
    float* out = (float*)d_out;

    const long long N  = in_sizes[0] / 256;   // 50000
    const long long E  = in_sizes[1] / 2;     // 800000
    const long long ET = E + N;
    const int nb = (int)((N + 255) / 256);

    // ---- workspace layout (256B aligned), ~112MB ----
    size_t off = 0;
    auto alloc = [&](size_t bytes) -> char* {
        size_t o = off;
        off += (bytes + 255) & ~(size_t)255;
        return (char*)d_ws + o;
    };
    int*   flag    = (int*)  alloc(256);
    float* sums    = (float*)alloc(2 * HC * sizeof(float));
    float* scale   = (float*)alloc(HC * sizeof(float));
    float* shift   = (float*)alloc(HC * sizeof(float));
    int*   bsumv   = (int*)  alloc(256 * sizeof(int));
    ushort_t* T1   = (ushort_t*)alloc(65536 * 2);
    ushort_t* Tm   = (ushort_t*)alloc(65536 * 2);
    ushort_t* Ts   = (ushort_t*)alloc(65536 * 2);
    float* esm     = (float*)alloc(N * NH * sizeof(float));
    float* edm     = (float*)alloc(N * NH * sizeof(float));
    float* ess     = (float*)alloc(N * NH * sizeof(float));
    float* eds     = (float*)alloc(N * NH * sizeof(float));
    int*   deg     = (int*)  alloc(N * sizeof(int));        // reused as cursor
    int*   rowptr  = (int*)  alloc((N + 1) * sizeof(int));
    int*   csr_src = (int*)  alloc(ET * sizeof(int));
    ushort_t* H1   = (ushort_t*)alloc(N * HC * 2);          // h1 bf16
    ushort_t* agg1 = (ushort_t*)alloc(N * HC * 2);          // agg1 bf16
    ushort_t* h2   = (ushort_t*)alloc(N * 512 * 2);         // [N,512] bf16 hm|hs
    (void)ws_size; (void)n_in; (void)out_size;

    const int M = (int)N;
    const int ggrid = (M + 127) / 128;
    dim3 wgrid(8, 8, 3);
    const long long egrid = (ET + 255) / 256;
    const long long agrid = (N + 3) / 4;

    init_k<<<nb, 256, 0, stream>>>(ei, E, N, flag, deg, sums);
    wconv_k<<<wgrid, 256, 0, stream>>>(W1, Wm, Ws, T1, Tm, Ts);

    // ---- CSR by destination ----
    hist_k<<<(int)egrid, 256, 0, stream>>>(ei, flag, E, ET, deg);
    scan1_k<<<nb, 256, 0, stream>>>(deg, rowptr, bsumv, N);     // also zeroes deg
    scan2_k<<<1, 256, 0, stream>>>(bsumv, nb);
    scan3_k<<<nb + 1, 256, 0, stream>>>(rowptr, bsumv, N, ET);
    scatter_k<<<(int)egrid, 256, 0, stream>>>(ei, flag, E, ET, rowptr, deg, csr_src);

    // ---- layer 1: GEMM(+scores) -> gather(bf16) -> stats -> scale/shift ----
    gemm_bf_k<0><<<dim3(ggrid, 1, 1), 256, 0, stream>>>(
        x, nullptr, T1, T1, H1, HC, nullptr, nullptr,
        a_src1, a_dst1, nullptr, nullptr, esm, edm, nullptr, nullptr, M);
    agg_concat_k<<<(int)agrid, 256, 0, stream>>>(rowptr, csr_src, esm, edm, H1, N, agg1);
    bn_stats_k<<<nb, 256, 0, stream>>>(agg1, b1, N, sums);
    bnfin_k<<<1, 256, 0, stream>>>(sums, b1, gamma1, beta1, N, scale, shift);

    // ---- layer 2: fused dual GEMM (BN on A-load, +scores) -> fused gather ----
    gemm_bf_k<1><<<dim3(ggrid, 1, 2), 256, 0, stream>>>(
        nullptr, agg1, Tm, Ts, h2, 512, scale, shift,
        am_src, am_dst, as_src, as_dst, esm, edm, ess, eds, M);
    agg_mean2_k<<<(int)agrid, 256, 0, stream>>>(rowptr, csr_src, esm, edm, ess, eds,
                                                h2, bm, bs, N, out);
}